// Round 8
// baseline (2758.067 us; speedup 1.0000x reference)
//
#include <hip/hip_runtime.h>

typedef unsigned short u16;
typedef unsigned int u32;
typedef __attribute__((ext_vector_type(8))) short short8;
typedef __attribute__((ext_vector_type(4))) float f32x4;

#define THR2 1e-4f   // THR^2, THR=0.01

__device__ __forceinline__ u16 f2bf(float f) {
    u32 u = __float_as_uint(f);
    u32 r = u + 0x7fffu + ((u >> 16) & 1u);   // round-to-nearest-even
    return (u16)(r >> 16);
}
__device__ __forceinline__ float bf2f(u16 h) { return __uint_as_float(((u32)h) << 16); }
__device__ __forceinline__ float lo16(u32 u) { return __uint_as_float(u << 16); }
__device__ __forceinline__ float hi16(u32 u) { return __uint_as_float(u & 0xffff0000u); }

// async global->LDS, 16B per lane. LDS dest must be wave-uniform base + lane*16.
__device__ __forceinline__ void gl_lds16(const u16* g, u16* l) {
    __builtin_amdgcn_global_load_lds(
        (const __attribute__((address_space(1))) void*)g,
        (__attribute__((address_space(3))) void*)l, 16, 0, 0);
}

// ---------------- small init / CSR-build kernels ----------------

__global__ void k_zero2(int* a, int* b, int n, int* flags) {
    int i = blockIdx.x * 256 + threadIdx.x;
    if (blockIdx.x == 0 && threadIdx.x < 64) flags[threadIdx.x] = 0;
    if (i < n) { a[i] = 0; b[i] = 0; }
}

__global__ void k_hist2(const int* __restrict__ adst, const int* __restrict__ ndst,
                        int* ca, int* cn, int E) {
    int e = blockIdx.x * 256 + threadIdx.x;
    if (e < E) {
        atomicAdd(&ca[adst[e]], 1);
        atomicAdd(&cn[ndst[e]], 1);
    }
}

__global__ void k_scan_p1(const int* __restrict__ cnt, int* bs, int n) {
    __shared__ int s[256];
    int i = blockIdx.x * 256 + threadIdx.x;
    s[threadIdx.x] = (i < n) ? cnt[i] : 0;
    __syncthreads();
    for (int off = 128; off > 0; off >>= 1) {
        if (threadIdx.x < off) s[threadIdx.x] += s[threadIdx.x + off];
        __syncthreads();
    }
    if (threadIdx.x == 0) bs[blockIdx.x] = s[0];
}

__global__ void k_scan_p2(int* bs, int nb, int* rp, int n) {
    if (threadIdx.x == 0 && blockIdx.x == 0) {
        int run = 0;
        for (int b = 0; b < nb; ++b) { int t = bs[b]; bs[b] = run; run += t; }
        rp[n] = run;
    }
}

__global__ void k_scan_p3(const int* __restrict__ cnt, const int* __restrict__ bs,
                          int* rp, int* cur, int n) {
    __shared__ int s[256];
    int i = blockIdx.x * 256 + threadIdx.x;
    int v = (i < n) ? cnt[i] : 0;
    s[threadIdx.x] = v;
    __syncthreads();
    for (int off = 1; off < 256; off <<= 1) {
        int t = (threadIdx.x >= off) ? s[threadIdx.x - off] : 0;
        __syncthreads();
        s[threadIdx.x] += t;
        __syncthreads();
    }
    int excl = s[threadIdx.x] - v + bs[blockIdx.x];
    if (i < n) { rp[i] = excl; cur[i] = excl; }
}

// CSR fill with PACKED (col,val) payload; nt hint on the random scatter stores
__global__ void k_fill2(const int* __restrict__ asrc, const int* __restrict__ adst,
                        const float* __restrict__ avals,
                        int* curA, int2* __restrict__ cvA,
                        const int* __restrict__ ndst, const float* __restrict__ nvals,
                        int* curN, int2* __restrict__ cvN, int E) {
    int e = blockIdx.x * 256 + threadIdx.x;
    if (e < E) {
        int p = atomicAdd(&curA[adst[e]], 1);
        long long pa = ((long long)__float_as_int(avals[e]) << 32) | (u32)asrc[e];
        __builtin_nontemporal_store(pa, (long long*)(cvA + p));
        int q = atomicAdd(&curN[ndst[e]], 1);
        long long pn = ((long long)__float_as_int(nvals[e]) << 32) | (u32)e;
        __builtin_nontemporal_store(pn, (long long*)(cvN + q));
    }
}

// ---------------- merged weight packing (fp32 -> bf16, transposed to [N][K]) --------
// ranges: [0,131072) W1sel | [131072,294912) W1base | [294912,360448) W2 | [360448,491520) Wo1

__global__ void k_pack_all(const float* __restrict__ Ws1, const float* __restrict__ Ws2,
                           const float* __restrict__ Wo1,
                           u16* W1selT, u16* W1baseT, u16* W2T, u16* Wo1T) {
    int i = blockIdx.x * 256 + threadIdx.x;
    if (i < 131072) {
        int n = i >> 8, k = i & 255;
        int r = (k < 128) ? k : k + 128;
        W1selT[i] = f2bf(Ws1[r * 512 + n]);
    } else if (i < 294912) {
        int t = i - 131072;
        int n = t / 320, k = t % 320;
        int r = (k < 128) ? (k + 128) : (k + 256);
        W1baseT[t] = f2bf(Ws1[r * 512 + n]);
    } else if (i < 360448) {
        int t = i - 294912;
        int n = t >> 9, k = t & 511;
        W2T[t] = f2bf(Ws2[k * 128 + n]);
    } else if (i < 491520) {
        int t = i - 360448;
        int n = t >> 8, k = t & 255;
        Wo1T[t] = f2bf(Wo1[k * 512 + n]);
    }
}

// ---------------- merged conversions: X0 nodes-cols, SA0 from state_init, SA2 ones ----

__global__ void k_conv_all(const float* __restrict__ nodes, const float* __restrict__ st,
                           u16* X0, u16* SA0, u16* SA2, int N) {
    int i = blockIdx.x * 256 + threadIdx.x;
    int total = N * 32;
    if (i < total) {
        int r = i >> 5, c4 = i & 31;
        float4 f = *(const float4*)(nodes + (size_t)r * 128 + c4 * 4);
        uint2 o;
        o.x = ((u32)f2bf(f.y) << 16) | f2bf(f.x);
        o.y = ((u32)f2bf(f.w) << 16) | f2bf(f.z);
        *(uint2*)(X0 + (size_t)r * 320 + c4 * 4) = o;
    } else if (i < 2 * total) {
        int t = i - total;
        int r = t >> 5, c4 = t & 31;
        float4 f = *(const float4*)(st + (size_t)r * 128 + c4 * 4);
        uint2 o;
        o.x = ((u32)f2bf(f.y) << 16) | f2bf(f.x);
        o.y = ((u32)f2bf(f.w) << 16) | f2bf(f.z);
        *(uint2*)(SA0 + (size_t)r * 256 + c4 * 4) = o;
    } else if (i < 3 * total) {
        int t = i - 2 * total;
        int r = t >> 5, c4 = t & 31;
        uint2 o; o.x = 0x3f803f80u; o.y = 0x3f803f80u;
        *(uint2*)(SA2 + (size_t)r * 256 + c4 * 4) = o;
    }
}

__global__ void k_build_fa(const u16* __restrict__ SA1, const float* __restrict__ nodes,
                           u16* FA, int N) {
    int i = blockIdx.x * 256 + threadIdx.x;   // N*64
    if (i >= N * 64) return;
    int r = i >> 6, c = i & 63;
    if (c < 32) {
        uint2 o = *(const uint2*)(SA1 + (size_t)r * 256 + c * 4);
        *(uint2*)(FA + (size_t)r * 256 + c * 4) = o;
    } else {
        float4 f = *(const float4*)(nodes + (size_t)r * 128 + (c - 32) * 4);
        uint2 o;
        o.x = ((u32)f2bf(f.y) << 16) | f2bf(f.x);
        o.y = ((u32)f2bf(f.w) << 16) | f2bf(f.z);
        *(uint2*)(FA + (size_t)r * 256 + c * 4) = o;
    }
}

// ---------------- constant aggregations (unchanged from benched r6) ----------------

__global__ void k_agg_const(const int* __restrict__ rpA, const int2* __restrict__ cvA,
                            const float* __restrict__ nodes,
                            const int* __restrict__ rpN, const int2* __restrict__ cvN,
                            const float* __restrict__ arcs,
                            u16* X0, int N) {
    int row = blockIdx.x * 4 + (threadIdx.x >> 6);
    if (row >= N) return;
    int l = threadIdx.x & 63;
    int h = l >> 4;        // edge slot 0..3
    int lc = l & 15;       // column lane-group index
    if (blockIdx.y == 0) {
        float b0 = 0.f, b1 = 0.f, b2 = 0.f, b3 = 0.f;
        float b4 = 0.f, b5 = 0.f, b6 = 0.f, b7 = 0.f;
        int s = rpA[row], e = rpA[row + 1];
        int j = s;
        for (; j + 8 <= e; j += 8) {
            int2 p0 = cvA[j + h], p1 = cvA[j + 4 + h];
            const float* r0 = nodes + (size_t)p0.x * 128 + 8 * lc;
            const float* r1 = nodes + (size_t)p1.x * 128 + 8 * lc;
            float4 f0a = *(const float4*)(r0), f0b = *(const float4*)(r0 + 4);
            float4 f1a = *(const float4*)(r1), f1b = *(const float4*)(r1 + 4);
            float v0 = __int_as_float(p0.y), v1 = __int_as_float(p1.y);
            b0 += v0 * f0a.x + v1 * f1a.x;  b1 += v0 * f0a.y + v1 * f1a.y;
            b2 += v0 * f0a.z + v1 * f1a.z;  b3 += v0 * f0a.w + v1 * f1a.w;
            b4 += v0 * f0b.x + v1 * f1b.x;  b5 += v0 * f0b.y + v1 * f1b.y;
            b6 += v0 * f0b.z + v1 * f1b.z;  b7 += v0 * f0b.w + v1 * f1b.w;
        }
        for (; j + 4 <= e; j += 4) {
            int2 pp = cvA[j + h];
            const float* r0 = nodes + (size_t)pp.x * 128 + 8 * lc;
            float4 fa = *(const float4*)(r0), fb = *(const float4*)(r0 + 4);
            float v = __int_as_float(pp.y);
            b0 += v * fa.x; b1 += v * fa.y; b2 += v * fa.z; b3 += v * fa.w;
            b4 += v * fb.x; b5 += v * fb.y; b6 += v * fb.z; b7 += v * fb.w;
        }
        if (h < e - j) {
            int2 pp = cvA[j + h];
            const float* r0 = nodes + (size_t)pp.x * 128 + 8 * lc;
            float4 fa = *(const float4*)(r0), fb = *(const float4*)(r0 + 4);
            float v = __int_as_float(pp.y);
            b0 += v * fa.x; b1 += v * fa.y; b2 += v * fa.z; b3 += v * fa.w;
            b4 += v * fb.x; b5 += v * fb.y; b6 += v * fb.z; b7 += v * fb.w;
        }
        b0 += __shfl_xor(b0, 16); b0 += __shfl_xor(b0, 32);
        b1 += __shfl_xor(b1, 16); b1 += __shfl_xor(b1, 32);
        b2 += __shfl_xor(b2, 16); b2 += __shfl_xor(b2, 32);
        b3 += __shfl_xor(b3, 16); b3 += __shfl_xor(b3, 32);
        b4 += __shfl_xor(b4, 16); b4 += __shfl_xor(b4, 32);
        b5 += __shfl_xor(b5, 16); b5 += __shfl_xor(b5, 32);
        b6 += __shfl_xor(b6, 16); b6 += __shfl_xor(b6, 32);
        b7 += __shfl_xor(b7, 16); b7 += __shfl_xor(b7, 32);
        if (h == 0) {
            uint4 o;
            o.x = ((u32)f2bf(b1) << 16) | f2bf(b0);
            o.y = ((u32)f2bf(b3) << 16) | f2bf(b2);
            o.z = ((u32)f2bf(b5) << 16) | f2bf(b4);
            o.w = ((u32)f2bf(b7) << 16) | f2bf(b6);
            *(uint4*)(X0 + (size_t)row * 320 + 128 + 8 * lc) = o;
        }
    } else {
        float c0 = 0.f, c1 = 0.f, c2 = 0.f, c3 = 0.f;
        int s = rpN[row], e = rpN[row + 1];
        int j = s;
        for (; j + 8 <= e; j += 8) {
            int2 p0 = cvN[j + h], p1 = cvN[j + 4 + h];
            const float* r0 = arcs + (size_t)p0.x * 66 + 2 + 4 * lc;
            const float* r1 = arcs + (size_t)p1.x * 66 + 2 + 4 * lc;
            float2 f0a = *(const float2*)(r0), f0b = *(const float2*)(r0 + 2);
            float2 f1a = *(const float2*)(r1), f1b = *(const float2*)(r1 + 2);
            float v0 = __int_as_float(p0.y), v1 = __int_as_float(p1.y);
            c0 += v0 * f0a.x + v1 * f1a.x;  c1 += v0 * f0a.y + v1 * f1a.y;
            c2 += v0 * f0b.x + v1 * f1b.x;  c3 += v0 * f0b.y + v1 * f1b.y;
        }
        for (; j + 4 <= e; j += 4) {
            int2 pp = cvN[j + h];
            const float* r0 = arcs + (size_t)pp.x * 66 + 2 + 4 * lc;
            float2 fa = *(const float2*)(r0), fb = *(const float2*)(r0 + 2);
            float v = __int_as_float(pp.y);
            c0 += v * fa.x; c1 += v * fa.y; c2 += v * fb.x; c3 += v * fb.y;
        }
        if (h < e - j) {
            int2 pp = cvN[j + h];
            const float* r0 = arcs + (size_t)pp.x * 66 + 2 + 4 * lc;
            float2 fa = *(const float2*)(r0), fb = *(const float2*)(r0 + 2);
            float v = __int_as_float(pp.y);
            c0 += v * fa.x; c1 += v * fa.y; c2 += v * fb.x; c3 += v * fb.y;
        }
        c0 += __shfl_xor(c0, 16); c0 += __shfl_xor(c0, 32);
        c1 += __shfl_xor(c1, 16); c1 += __shfl_xor(c1, 32);
        c2 += __shfl_xor(c2, 16); c2 += __shfl_xor(c2, 32);
        c3 += __shfl_xor(c3, 16); c3 += __shfl_xor(c3, 32);
        if (h == 0) {
            uint2 o;
            o.x = ((u32)f2bf(c1) << 16) | f2bf(c0);
            o.y = ((u32)f2bf(c3) << 16) | f2bf(c2);
            *(uint2*)(X0 + (size_t)row * 320 + 256 + 4 * lc) = o;
        }
    }
}

// ---------------- agg_states spmm (unchanged from benched r6) ----------------

__global__ void k_spmm_state(const int* __restrict__ rp, const int2* __restrict__ cv,
                             const u16* __restrict__ state, u16* agg, int N,
                             const int* __restrict__ anyf, const int* __restrict__ contprev,
                             int* contout) {
    int a = *anyf;
    int p = contprev ? *contprev : 1;
    int c = (a && p) ? 1 : 0;
    if (blockIdx.x == 0 && threadIdx.x == 0) *contout = c;
    if (!c) return;
    int row = blockIdx.x * 4 + (threadIdx.x >> 6);
    if (row >= N) return;
    int l = threadIdx.x & 63;
    int h = l >> 4;        // edge slot 0..3
    int lc = l & 15;       // u16 cols [8lc, 8lc+8)
    float a0 = 0.f, a1 = 0.f, a2 = 0.f, a3 = 0.f;
    float a4 = 0.f, a5 = 0.f, a6 = 0.f, a7 = 0.f;
    int s = rp[row], e = rp[row + 1];
    int j = s;
    for (; j + 16 <= e; j += 16) {
        int2 p0 = cv[j + h],      p1 = cv[j + 4 + h];
        int2 p2 = cv[j + 8 + h],  p3 = cv[j + 12 + h];
        uint4 u0 = *(const uint4*)(state + (size_t)p0.x * 256 + 8 * lc);
        uint4 u1 = *(const uint4*)(state + (size_t)p1.x * 256 + 8 * lc);
        uint4 u2 = *(const uint4*)(state + (size_t)p2.x * 256 + 8 * lc);
        uint4 u3 = *(const uint4*)(state + (size_t)p3.x * 256 + 8 * lc);
        float v0 = __int_as_float(p0.y), v1 = __int_as_float(p1.y);
        float v2 = __int_as_float(p2.y), v3 = __int_as_float(p3.y);
        a0 += v0 * lo16(u0.x) + v1 * lo16(u1.x) + v2 * lo16(u2.x) + v3 * lo16(u3.x);
        a1 += v0 * hi16(u0.x) + v1 * hi16(u1.x) + v2 * hi16(u2.x) + v3 * hi16(u3.x);
        a2 += v0 * lo16(u0.y) + v1 * lo16(u1.y) + v2 * lo16(u2.y) + v3 * lo16(u3.y);
        a3 += v0 * hi16(u0.y) + v1 * hi16(u1.y) + v2 * hi16(u2.y) + v3 * hi16(u3.y);
        a4 += v0 * lo16(u0.z) + v1 * lo16(u1.z) + v2 * lo16(u2.z) + v3 * lo16(u3.z);
        a5 += v0 * hi16(u0.z) + v1 * hi16(u1.z) + v2 * hi16(u2.z) + v3 * hi16(u3.z);
        a6 += v0 * lo16(u0.w) + v1 * lo16(u1.w) + v2 * lo16(u2.w) + v3 * lo16(u3.w);
        a7 += v0 * hi16(u0.w) + v1 * hi16(u1.w) + v2 * hi16(u2.w) + v3 * hi16(u3.w);
    }
    for (; j + 8 <= e; j += 8) {
        int2 p0 = cv[j + h], p1 = cv[j + 4 + h];
        uint4 u0 = *(const uint4*)(state + (size_t)p0.x * 256 + 8 * lc);
        uint4 u1 = *(const uint4*)(state + (size_t)p1.x * 256 + 8 * lc);
        float v0 = __int_as_float(p0.y), v1 = __int_as_float(p1.y);
        a0 += v0 * lo16(u0.x) + v1 * lo16(u1.x);
        a1 += v0 * hi16(u0.x) + v1 * hi16(u1.x);
        a2 += v0 * lo16(u0.y) + v1 * lo16(u1.y);
        a3 += v0 * hi16(u0.y) + v1 * hi16(u1.y);
        a4 += v0 * lo16(u0.z) + v1 * lo16(u1.z);
        a5 += v0 * hi16(u0.z) + v1 * hi16(u1.z);
        a6 += v0 * lo16(u0.w) + v1 * lo16(u1.w);
        a7 += v0 * hi16(u0.w) + v1 * hi16(u1.w);
    }
    for (; j + 4 <= e; j += 4) {
        int2 pp = cv[j + h];
        uint4 u = *(const uint4*)(state + (size_t)pp.x * 256 + 8 * lc);
        float v = __int_as_float(pp.y);
        a0 += v * lo16(u.x); a1 += v * hi16(u.x);
        a2 += v * lo16(u.y); a3 += v * hi16(u.y);
        a4 += v * lo16(u.z); a5 += v * hi16(u.z);
        a6 += v * lo16(u.w); a7 += v * hi16(u.w);
    }
    if (h < e - j) {
        int2 pp = cv[j + h];
        uint4 u = *(const uint4*)(state + (size_t)pp.x * 256 + 8 * lc);
        float v = __int_as_float(pp.y);
        a0 += v * lo16(u.x); a1 += v * hi16(u.x);
        a2 += v * lo16(u.y); a3 += v * hi16(u.y);
        a4 += v * lo16(u.z); a5 += v * hi16(u.z);
        a6 += v * lo16(u.w); a7 += v * hi16(u.w);
    }
    a0 += __shfl_xor(a0, 16); a0 += __shfl_xor(a0, 32);
    a1 += __shfl_xor(a1, 16); a1 += __shfl_xor(a1, 32);
    a2 += __shfl_xor(a2, 16); a2 += __shfl_xor(a2, 32);
    a3 += __shfl_xor(a3, 16); a3 += __shfl_xor(a3, 32);
    a4 += __shfl_xor(a4, 16); a4 += __shfl_xor(a4, 32);
    a5 += __shfl_xor(a5, 16); a5 += __shfl_xor(a5, 32);
    a6 += __shfl_xor(a6, 16); a6 += __shfl_xor(a6, 32);
    a7 += __shfl_xor(a7, 16); a7 += __shfl_xor(a7, 32);
    if (h == 0) {
        uint4 o;
        o.x = ((u32)f2bf(a1) << 16) | f2bf(a0);
        o.y = ((u32)f2bf(a3) << 16) | f2bf(a2);
        o.z = ((u32)f2bf(a5) << 16) | f2bf(a4);
        o.w = ((u32)f2bf(a7) << 16) | f2bf(a6);
        *(uint4*)(agg + (size_t)row * 256 + 8 * lc) = o;
    }
}

// ---------------- convergence check (used once, t=0) ----------------

__global__ void k_check(const u16* __restrict__ cur, const u16* __restrict__ prev,
                        int N, int* anyf) {
    int row = blockIdx.x * 4 + (threadIdx.x >> 6);
    int l = threadIdx.x & 63;
    float d2 = 0.f, n2 = 0.f;
    if (row < N) {
        u32 u1 = *(const u32*)(cur + (size_t)row * 256 + 2 * l);
        u32 u2 = *(const u32*)(prev + (size_t)row * 256 + 2 * l);
        float ax = lo16(u1), ay = hi16(u1);
        float bx = lo16(u2), by = hi16(u2);
        float dx = ax - bx, dy = ay - by;
        d2 = dx * dx + dy * dy;
        n2 = bx * bx + by * by;
    }
    for (int off = 32; off; off >>= 1) {
        d2 += __shfl_down(d2, off);
        n2 += __shfl_down(n2, off);
    }
    if (l == 0 && row < N && d2 > THR2 * n2) {
        volatile int* f = (volatile int*)anyf;
        if (*f == 0) atomicOr(anyf, 1);   // stale-0 read => harmless extra atomic
    }
}

// ---------------- MFMA GEMM: D = epi(A @ BT^T), 128x128 tiles, BK=64 --------------
// global_load_lds staging (16B/lane), LDS linear [128][64] + SOURCE-XOR swizzle:
// LDS[r][c8] holds global chunk (c8 ^ (r&7)) of row r (chunk = 8 elems = 16B).
// Fragment read applies the same XOR -> 2 lanes/bank-group (free). Same ascending
// k accumulation order as BK=32 version => bit-identical numerics.
// Barriers per launch halved vs BK=32 (one vmcnt(0)-drain pair per 64-wide step).
// M-edge: staged row clamped to M-1; garbage rows only feed guarded stores.
// skipmode: 0 = always run, 1 = return if *contflag==0, 2 = copy state if *contflag==0
// chk != nullptr (gemm2 only, grid.y==1): fused NEXT-iter convergence check.

__global__ __launch_bounds__(256)
void k_gemm(const u16* __restrict__ A, int lda,
            const u16* __restrict__ BT, int ldb,
            const float* __restrict__ bias,
            const u16* __restrict__ Cadd, int ldc,
            u16* __restrict__ D, int ldd,
            int M, int K, int dotanh,
            const int* __restrict__ contflag, int skipmode,
            const u16* __restrict__ copysrc, u16* __restrict__ copydst,
            int* chk) {
    int m0 = blockIdx.x * 128;
    int n0 = blockIdx.y * 128;
    if (skipmode && *contflag == 0) {
        if (skipmode == 2) {
            for (int c = threadIdx.x; c < 2048; c += 256) {
                int r = c >> 4, ch = (c & 15) * 8;
                int row = m0 + r;
                if (row < M)
                    *(uint4*)(copydst + (size_t)row * 256 + ch) =
                        *(const uint4*)(copysrc + (size_t)row * 256 + ch);
            }
        }
        return;   // converged: chk stays 0 => stays converged
    }
    __shared__ u16 As[128 * 64];
    __shared__ u16 Bs[128 * 64];
    __shared__ float rsum[256];   // [0..127]=d2, [128..255]=n2
    int tid = threadIdx.x;
    int wave = tid >> 6, l = tid & 63;
    int wm = (wave >> 1) * 64, wn = (wave & 1) * 64;
    int ml = l & 15, kg = l >> 4;
    f32x4 acc[4][4];
#pragma unroll
    for (int mi = 0; mi < 4; ++mi)
#pragma unroll
        for (int ni = 0; ni < 4; ++ni) acc[mi][ni] = (f32x4){0.f, 0.f, 0.f, 0.f};

    if (chk) rsum[tid] = 0.f;

    for (int k0 = 0; k0 < K; k0 += 64) {
#pragma unroll
        for (int i = 0; i < 4; ++i) {
            int c = tid + i * 256;            // chunk 0..1023; 16B each
            int r = c >> 3, c8 = c & 7;
            int sw = ((c8 ^ (r & 7)) << 3);   // source-XOR-swizzled k-offset (elems)
            int rowA = m0 + r; rowA = (rowA < M) ? rowA : (M - 1);
            gl_lds16(A + (size_t)rowA * lda + k0 + sw, &As[c * 8]);
            gl_lds16(BT + (size_t)(n0 + r) * ldb + k0 + sw, &Bs[c * 8]);
        }
        __syncthreads();
#pragma unroll
        for (int kk = 0; kk < 2; ++kk) {
            short8 av[4], bv[4];
#pragma unroll
            for (int mi = 0; mi < 4; ++mi) {
                int row = wm + mi * 16 + ml;
                int q = ((kk * 4 + kg) ^ (row & 7)) << 3;
                av[mi] = *(const short8*)(&As[row * 64 + q]);
            }
#pragma unroll
            for (int ni = 0; ni < 4; ++ni) {
                int row = wn + ni * 16 + ml;
                int q = ((kk * 4 + kg) ^ (row & 7)) << 3;
                bv[ni] = *(const short8*)(&Bs[row * 64 + q]);
            }
#pragma unroll
            for (int mi = 0; mi < 4; ++mi)
#pragma unroll
                for (int ni = 0; ni < 4; ++ni)
                    acc[mi][ni] = __builtin_amdgcn_mfma_f32_16x16x32_bf16(
                        av[mi], bv[ni], acc[mi][ni], 0, 0, 0);
        }
        __syncthreads();
    }
    // epilogue (mi, r outer so per-row check partials accumulate over ni)
#pragma unroll
    for (int mi = 0; mi < 4; ++mi) {
#pragma unroll
        for (int r = 0; r < 4; ++r) {
            int row = m0 + wm + mi * 16 + kg * 4 + r;
            bool ok = row < M;
            float d2l = 0.f, n2l = 0.f;
#pragma unroll
            for (int ni = 0; ni < 4; ++ni) {
                int col = n0 + wn + ni * 16 + ml;
                if (ok) {
                    float v = acc[mi][ni][r];
                    if (bias) v += bias[col];
                    if (Cadd) v += bf2f(Cadd[(size_t)row * ldc + col]);
                    if (dotanh) v = tanhf(v);
                    u16 hb = f2bf(v);
                    D[(size_t)row * ldd + col] = hb;
                    if (chk) {
                        float vq = bf2f(hb);
                        float o  = bf2f(copysrc[(size_t)row * 256 + col]);
                        float d = vq - o;
                        d2l += d * d;
                        n2l += o * o;
                    }
                }
            }
            if (chk) {
#pragma unroll
                for (int off = 1; off < 16; off <<= 1) {
                    d2l += __shfl_xor(d2l, off);
                    n2l += __shfl_xor(n2l, off);
                }
                if (ml == 0) {
                    int lrow = wm + mi * 16 + kg * 4 + r;
                    atomicAdd(&rsum[lrow], d2l);
                    atomicAdd(&rsum[128 + lrow], n2l);
                }
            }
        }
    }
    if (chk) {
        __syncthreads();
        bool viol = false;
        if (tid < 128) {
            int row = m0 + tid;
            if (row < M) viol = rsum[tid] > THR2 * rsum[128 + tid];
        }
        if (__any(viol) && (threadIdx.x & 63) == 0) {
            volatile int* f = (volatile int*)chk;
            if (*f == 0) atomicOr(chk, 1);
        }
    }
}

// ---------------- final tiny-N output GEMM: out = (HO @ Wo2 + bo2) * mask ----------

__global__ void k_out(const u16* __restrict__ HO, const float* __restrict__ Wo2,
                      const float* __restrict__ bo2,
                      const int* __restrict__ m1,
                      const int* __restrict__ m2,
                      float* __restrict__ out, int N) {
    __shared__ float w[512 * 7];
    for (int i = threadIdx.x; i < 512 * 7; i += 256) w[i] = Wo2[i];
    __syncthreads();
    int row = blockIdx.x * 4 + (threadIdx.x >> 6);
    if (row >= N) return;
    int l = threadIdx.x & 63;
    uint4 u = *(const uint4*)(HO + (size_t)row * 512 + l * 8);
    float h[8];
    h[0] = lo16(u.x); h[1] = hi16(u.x);
    h[2] = lo16(u.y); h[3] = hi16(u.y);
    h[4] = lo16(u.z); h[5] = hi16(u.z);
    h[6] = lo16(u.w); h[7] = hi16(u.w);
    float a[7] = {0.f, 0.f, 0.f, 0.f, 0.f, 0.f, 0.f};
#pragma unroll
    for (int i = 0; i < 8; ++i) {
        int base = (l * 8 + i) * 7;
#pragma unroll
        for (int j = 0; j < 7; ++j) a[j] += h[i] * w[base + j];
    }
    for (int off = 32; off; off >>= 1) {
#pragma unroll
        for (int j = 0; j < 7; ++j) a[j] += __shfl_down(a[j], off);
    }
    if (l == 0) {
        float mm = (m1[row] != 0 && m2[row] != 0) ? 1.f : 0.f;
#pragma unroll
        for (int j = 0; j < 7; ++j) out[(size_t)row * 7 + j] = (a[j] + bo2[j]) * mm;
    }
}

// ---------------- launch ----------------

extern "C" void kernel_launch(void* const* d_in, const int* in_sizes, int n_in,
                              void* d_out, int out_size, void* d_ws, size_t ws_size,
                              hipStream_t stream) {
    const float* nodes   = (const float*)d_in[0];
    const float* arcs    = (const float*)d_in[1];
    const int*   set_mask    = (const int*)d_in[2];
    const int*   output_mask = (const int*)d_in[3];
    const int*   adj_src = (const int*)d_in[4];
    const int*   adj_dst = (const int*)d_in[5];
    const float* adj_vals= (const float*)d_in[6];
    const int*   an_dst  = (const int*)d_in[7];
    const float* an_vals = (const float*)d_in[8];
    const float* state_init = (const float*)d_in[9];
    const float* Ws1 = (const float*)d_in[10];
    const float* bs1 = (const float*)d_in[11];
    const float* Ws2 = (const float*)d_in[12];
    const float* bs2 = (const float*)d_in[13];
    const float* Wo1 = (const float*)d_in[14];
    const float* bo1 = (const float*)d_in[15];
    const float* Wo2 = (const float*)d_in[16];
    const float* bo2 = (const float*)d_in[17];
    float* out = (float*)d_out;

    const int N = in_sizes[2];     // 50000
    const int E = in_sizes[4];     // 640000

    char* ws = (char*)d_ws;
    size_t off = 0;
    auto alloc = [&](size_t bytes) {
        char* p = ws + off;
        off += (bytes + 255) & ~(size_t)255;
        return p;
    };
    u16* SA0 = (u16*)alloc((size_t)N * 256 * 2);
    u16* SA1 = (u16*)alloc((size_t)N * 256 * 2);
    u16* SA2 = (u16*)alloc((size_t)N * 256 * 2);
    u16* CB  = (u16*)alloc((size_t)N * 512 * 2);
    u16* HID = (u16*)alloc((size_t)N * 512 * 2);
    u16* X0  = HID;                 // X0 (N x 320) aliases HID; consumed before HID first write
    u16* FA  = SA0;                 // final [state|nodes] aliases SA0 (free after iter 9)
    u16* W1selT  = (u16*)alloc(512 * 256 * 2);
    u16* W1baseT = (u16*)alloc(512 * 320 * 2);
    u16* W2T     = (u16*)alloc(128 * 512 * 2);
    u16* Wo1T    = (u16*)alloc(512 * 256 * 2);
    int* rpA  = (int*)alloc((size_t)(N + 1) * 4);
    int* curA = (int*)alloc((size_t)N * 4);
    int* cntA = (int*)alloc((size_t)N * 4);
    int2* cvA = (int2*)alloc((size_t)E * 8);
    int* rpN  = (int*)alloc((size_t)(N + 1) * 4);
    int* curN = (int*)alloc((size_t)N * 4);
    int* cntN = (int*)alloc((size_t)N * 4);
    int2* cvN = (int2*)alloc((size_t)E * 8);
    int* bsA = (int*)alloc(256 * 4);
    int* bsN = (int*)alloc(256 * 4);
    int* flags = (int*)alloc(64 * 4);
    int* anyf = flags;          // [0..10]
    int* cont = flags + 16;     // [0..9]
    (void)ws_size; (void)n_in; (void)out_size;

    const int nb = (N + 255) / 256;
    const int gE = (E + 255) / 256;
    const int gRow = (N + 3) / 4;
    const int gx = (N + 127) / 128;

    // init + CSR build
    k_zero2<<<nb, 256, 0, stream>>>(cntA, cntN, N, flags);
    k_hist2<<<gE, 256, 0, stream>>>(adj_dst, an_dst, cntA, cntN, E);
    k_scan_p1<<<nb, 256, 0, stream>>>(cntA, bsA, N);
    k_scan_p2<<<1, 64, 0, stream>>>(bsA, nb, rpA, N);
    k_scan_p3<<<nb, 256, 0, stream>>>(cntA, bsA, rpA, curA, N);
    k_scan_p1<<<nb, 256, 0, stream>>>(cntN, bsN, N);
    k_scan_p2<<<1, 64, 0, stream>>>(bsN, nb, rpN, N);
    k_scan_p3<<<nb, 256, 0, stream>>>(cntN, bsN, rpN, curN, N);
    k_fill2<<<gE, 256, 0, stream>>>(adj_src, adj_dst, adj_vals, curA, cvA,
                                    an_dst, an_vals, curN, cvN, E);
    // merged weight packing (491520 elems)
    k_pack_all<<<1920, 256, 0, stream>>>(Ws1, Ws2, Wo1, W1selT, W1baseT, W2T, Wo1T);
    // merged conversions (3 * N*32 elems)
    k_conv_all<<<(3 * N * 32 + 255) / 256, 256, 0, stream>>>(nodes, state_init,
                                                             X0, SA0, SA2, N);
    // constant aggregations (fused: y=0 nodes, y=1 arcs)
    k_agg_const<<<dim3(gRow, 2), 256, 0, stream>>>(rpA, cvA, nodes,
                                                   rpN, cvN, arcs, X0, N);
    // C_base = X0 @ W1baseT^T + bs1   (no tanh)
    k_gemm<<<dim3(gx, 4), 256, 0, stream>>>(X0, 320, W1baseT, 320, bs1,
                                            nullptr, 0, CB, 512, N, 320, 0,
                                            nullptr, 0, nullptr, nullptr, nullptr);
    // 10 unrolled fixed-point iterations
    u16* SAs[3] = {SA0, SA1, SA2};
    for (int t = 0; t < 10; ++t) {
        u16* curS = SAs[t % 3];
        u16* prvS = SAs[(t + 2) % 3];
        u16* nxtS = SAs[(t + 1) % 3];
        if (t == 0)
            k_check<<<gRow, 256, 0, stream>>>(curS, prvS, N, anyf);
        // (for t>=1, anyf[t] was produced by the previous gemm2's fused check)
        k_spmm_state<<<gRow, 256, 0, stream>>>(rpA, cvA, curS, curS + 128, N,
                                               anyf + t, t ? (cont + t - 1) : nullptr,
                                               cont + t);
        // HID = tanh([state|agg] @ W1selT^T + C_base)
        k_gemm<<<dim3(gx, 4), 256, 0, stream>>>(curS, 256, W1selT, 256, nullptr,
                                                CB, 512, HID, 512, N, 256, 1,
                                                cont + t, 1, nullptr, nullptr, nullptr);
        // next_state = tanh(HID @ W2T^T + bs2); copy state if converged;
        // fused: anyf[t+1] = any(||next-cur||^2 > THR2*||cur||^2)
        k_gemm<<<dim3(gx, 1), 256, 0, stream>>>(HID, 512, W2T, 512, bs2,
                                                nullptr, 0, nxtS, 256, N, 512, 1,
                                                cont + t, 2, curS, nxtS, anyf + t + 1);
    }
    // final state is in SAs[10 % 3] = SA1
    k_build_fa<<<(N * 64 + 255) / 256, 256, 0, stream>>>(SA1, nodes, FA, N);
    k_gemm<<<dim3(gx, 4), 256, 0, stream>>>(FA, 256, Wo1T, 256, bo1,
                                            nullptr, 0, HID, 512, N, 256, 1,
                                            nullptr, 0, nullptr, nullptr, nullptr);
    k_out<<<gRow, 256, 0, stream>>>(HID, Wo2, bo2, set_mask, output_mask, out, N);
}

// Round 9
// 2436.376 us; speedup vs baseline: 1.1320x; 1.1320x over previous
//
#include <hip/hip_runtime.h>

typedef unsigned short u16;
typedef unsigned int u32;
typedef __attribute__((ext_vector_type(8))) short short8;
typedef __attribute__((ext_vector_type(4))) float f32x4;

#define THR2 1e-4f   // THR^2, THR=0.01

__device__ __forceinline__ u16 f2bf(float f) {
    u32 u = __float_as_uint(f);
    u32 r = u + 0x7fffu + ((u >> 16) & 1u);   // round-to-nearest-even
    return (u16)(r >> 16);
}
__device__ __forceinline__ float bf2f(u16 h) { return __uint_as_float(((u32)h) << 16); }
__device__ __forceinline__ float lo16(u32 u) { return __uint_as_float(u << 16); }
__device__ __forceinline__ float hi16(u32 u) { return __uint_as_float(u & 0xffff0000u); }

// async global->LDS, 16B per lane. LDS dest must be wave-uniform base + lane*16.
__device__ __forceinline__ void gl_lds16(const u16* g, u16* l) {
    __builtin_amdgcn_global_load_lds(
        (const __attribute__((address_space(1))) void*)g,
        (__attribute__((address_space(3))) void*)l, 16, 0, 0);
}

// ---------------- small init / CSR-build kernels ----------------

__global__ void k_zero2(int* a, int* b, int n, int* flags) {
    int i = blockIdx.x * 256 + threadIdx.x;
    if (blockIdx.x == 0 && threadIdx.x < 64) flags[threadIdx.x] = 0;
    if (i < n) { a[i] = 0; b[i] = 0; }
}

__global__ void k_hist2(const int* __restrict__ adst, const int* __restrict__ ndst,
                        int* ca, int* cn, int E) {
    int e = blockIdx.x * 256 + threadIdx.x;
    if (e < E) {
        atomicAdd(&ca[adst[e]], 1);
        atomicAdd(&cn[ndst[e]], 1);
    }
}

__global__ void k_scan_p1(const int* __restrict__ cnt, int* bs, int n) {
    __shared__ int s[256];
    int i = blockIdx.x * 256 + threadIdx.x;
    s[threadIdx.x] = (i < n) ? cnt[i] : 0;
    __syncthreads();
    for (int off = 128; off > 0; off >>= 1) {
        if (threadIdx.x < off) s[threadIdx.x] += s[threadIdx.x + off];
        __syncthreads();
    }
    if (threadIdx.x == 0) bs[blockIdx.x] = s[0];
}

__global__ void k_scan_p2(int* bs, int nb, int* rp, int n) {
    if (threadIdx.x == 0 && blockIdx.x == 0) {
        int run = 0;
        for (int b = 0; b < nb; ++b) { int t = bs[b]; bs[b] = run; run += t; }
        rp[n] = run;
    }
}

__global__ void k_scan_p3(const int* __restrict__ cnt, const int* __restrict__ bs,
                          int* rp, int* cur, int n) {
    __shared__ int s[256];
    int i = blockIdx.x * 256 + threadIdx.x;
    int v = (i < n) ? cnt[i] : 0;
    s[threadIdx.x] = v;
    __syncthreads();
    for (int off = 1; off < 256; off <<= 1) {
        int t = (threadIdx.x >= off) ? s[threadIdx.x - off] : 0;
        __syncthreads();
        s[threadIdx.x] += t;
        __syncthreads();
    }
    int excl = s[threadIdx.x] - v + bs[blockIdx.x];
    if (i < n) { rp[i] = excl; cur[i] = excl; }
}

// CSR fill with PACKED (col,val) payload; nt hint on the random scatter stores
__global__ void k_fill2(const int* __restrict__ asrc, const int* __restrict__ adst,
                        const float* __restrict__ avals,
                        int* curA, int2* __restrict__ cvA,
                        const int* __restrict__ ndst, const float* __restrict__ nvals,
                        int* curN, int2* __restrict__ cvN, int E) {
    int e = blockIdx.x * 256 + threadIdx.x;
    if (e < E) {
        int p = atomicAdd(&curA[adst[e]], 1);
        long long pa = ((long long)__float_as_int(avals[e]) << 32) | (u32)asrc[e];
        __builtin_nontemporal_store(pa, (long long*)(cvA + p));
        int q = atomicAdd(&curN[ndst[e]], 1);
        long long pn = ((long long)__float_as_int(nvals[e]) << 32) | (u32)e;
        __builtin_nontemporal_store(pn, (long long*)(cvN + q));
    }
}

// ---------------- merged weight packing (fp32 -> bf16, transposed to [N][K]) --------
// ranges: [0,131072) W1sel | [131072,294912) W1base | [294912,360448) W2 | [360448,491520) Wo1
// W2T k-dim uses the fragment permutation pi: stored k' holds original
// k = (k' & ~63) + (k'&3)*16 + ((k'&63)>>2)   (matches pi-layout HID).

__global__ void k_pack_all(const float* __restrict__ Ws1, const float* __restrict__ Ws2,
                           const float* __restrict__ Wo1,
                           u16* W1selT, u16* W1baseT, u16* W2T, u16* Wo1T) {
    int i = blockIdx.x * 256 + threadIdx.x;
    if (i < 131072) {
        int n = i >> 8, k = i & 255;
        int r = (k < 128) ? k : k + 128;
        W1selT[i] = f2bf(Ws1[r * 512 + n]);
    } else if (i < 294912) {
        int t = i - 131072;
        int n = t / 320, k = t % 320;
        int r = (k < 128) ? (k + 128) : (k + 256);
        W1baseT[t] = f2bf(Ws1[r * 512 + n]);
    } else if (i < 360448) {
        int t = i - 294912;
        int n = t >> 9, kp = t & 511;
        int q = kp & 63;
        int k = (kp & ~63) + ((q & 3) << 4) + (q >> 2);   // pi^-1
        W2T[t] = f2bf(Ws2[k * 128 + n]);
    } else if (i < 491520) {
        int t = i - 360448;
        int n = t >> 8, k = t & 255;
        Wo1T[t] = f2bf(Wo1[k * 512 + n]);
    }
}

// ---------------- merged conversions: X0 nodes-cols, SA0 from state_init, SA2 ones ----

__global__ void k_conv_all(const float* __restrict__ nodes, const float* __restrict__ st,
                           u16* X0, u16* SA0, u16* SA2, int N) {
    int i = blockIdx.x * 256 + threadIdx.x;
    int total = N * 32;
    if (i < total) {
        int r = i >> 5, c4 = i & 31;
        float4 f = *(const float4*)(nodes + (size_t)r * 128 + c4 * 4);
        uint2 o;
        o.x = ((u32)f2bf(f.y) << 16) | f2bf(f.x);
        o.y = ((u32)f2bf(f.w) << 16) | f2bf(f.z);
        *(uint2*)(X0 + (size_t)r * 320 + c4 * 4) = o;
    } else if (i < 2 * total) {
        int t = i - total;
        int r = t >> 5, c4 = t & 31;
        float4 f = *(const float4*)(st + (size_t)r * 128 + c4 * 4);
        uint2 o;
        o.x = ((u32)f2bf(f.y) << 16) | f2bf(f.x);
        o.y = ((u32)f2bf(f.w) << 16) | f2bf(f.z);
        *(uint2*)(SA0 + (size_t)r * 256 + c4 * 4) = o;
    } else if (i < 3 * total) {
        int t = i - 2 * total;
        int r = t >> 5, c4 = t & 31;
        uint2 o; o.x = 0x3f803f80u; o.y = 0x3f803f80u;
        *(uint2*)(SA2 + (size_t)r * 256 + c4 * 4) = o;
    }
}

__global__ void k_build_fa(const u16* __restrict__ SA1, const float* __restrict__ nodes,
                           u16* FA, int N) {
    int i = blockIdx.x * 256 + threadIdx.x;   // N*64
    if (i >= N * 64) return;
    int r = i >> 6, c = i & 63;
    if (c < 32) {
        uint2 o = *(const uint2*)(SA1 + (size_t)r * 256 + c * 4);
        *(uint2*)(FA + (size_t)r * 256 + c * 4) = o;
    } else {
        float4 f = *(const float4*)(nodes + (size_t)r * 128 + (c - 32) * 4);
        uint2 o;
        o.x = ((u32)f2bf(f.y) << 16) | f2bf(f.x);
        o.y = ((u32)f2bf(f.w) << 16) | f2bf(f.z);
        *(uint2*)(FA + (size_t)r * 256 + c * 4) = o;
    }
}

// ---------------- constant aggregations (unchanged from benched r6) ----------------

__global__ void k_agg_const(const int* __restrict__ rpA, const int2* __restrict__ cvA,
                            const float* __restrict__ nodes,
                            const int* __restrict__ rpN, const int2* __restrict__ cvN,
                            const float* __restrict__ arcs,
                            u16* X0, int N) {
    int row = blockIdx.x * 4 + (threadIdx.x >> 6);
    if (row >= N) return;
    int l = threadIdx.x & 63;
    int h = l >> 4;        // edge slot 0..3
    int lc = l & 15;       // column lane-group index
    if (blockIdx.y == 0) {
        float b0 = 0.f, b1 = 0.f, b2 = 0.f, b3 = 0.f;
        float b4 = 0.f, b5 = 0.f, b6 = 0.f, b7 = 0.f;
        int s = rpA[row], e = rpA[row + 1];
        int j = s;
        for (; j + 8 <= e; j += 8) {
            int2 p0 = cvA[j + h], p1 = cvA[j + 4 + h];
            const float* r0 = nodes + (size_t)p0.x * 128 + 8 * lc;
            const float* r1 = nodes + (size_t)p1.x * 128 + 8 * lc;
            float4 f0a = *(const float4*)(r0), f0b = *(const float4*)(r0 + 4);
            float4 f1a = *(const float4*)(r1), f1b = *(const float4*)(r1 + 4);
            float v0 = __int_as_float(p0.y), v1 = __int_as_float(p1.y);
            b0 += v0 * f0a.x + v1 * f1a.x;  b1 += v0 * f0a.y + v1 * f1a.y;
            b2 += v0 * f0a.z + v1 * f1a.z;  b3 += v0 * f0a.w + v1 * f1a.w;
            b4 += v0 * f0b.x + v1 * f1b.x;  b5 += v0 * f0b.y + v1 * f1b.y;
            b6 += v0 * f0b.z + v1 * f1b.z;  b7 += v0 * f0b.w + v1 * f1b.w;
        }
        for (; j + 4 <= e; j += 4) {
            int2 pp = cvA[j + h];
            const float* r0 = nodes + (size_t)pp.x * 128 + 8 * lc;
            float4 fa = *(const float4*)(r0), fb = *(const float4*)(r0 + 4);
            float v = __int_as_float(pp.y);
            b0 += v * fa.x; b1 += v * fa.y; b2 += v * fa.z; b3 += v * fa.w;
            b4 += v * fb.x; b5 += v * fb.y; b6 += v * fb.z; b7 += v * fb.w;
        }
        if (h < e - j) {
            int2 pp = cvA[j + h];
            const float* r0 = nodes + (size_t)pp.x * 128 + 8 * lc;
            float4 fa = *(const float4*)(r0), fb = *(const float4*)(r0 + 4);
            float v = __int_as_float(pp.y);
            b0 += v * fa.x; b1 += v * fa.y; b2 += v * fa.z; b3 += v * fa.w;
            b4 += v * fb.x; b5 += v * fb.y; b6 += v * fb.z; b7 += v * fb.w;
        }
        b0 += __shfl_xor(b0, 16); b0 += __shfl_xor(b0, 32);
        b1 += __shfl_xor(b1, 16); b1 += __shfl_xor(b1, 32);
        b2 += __shfl_xor(b2, 16); b2 += __shfl_xor(b2, 32);
        b3 += __shfl_xor(b3, 16); b3 += __shfl_xor(b3, 32);
        b4 += __shfl_xor(b4, 16); b4 += __shfl_xor(b4, 32);
        b5 += __shfl_xor(b5, 16); b5 += __shfl_xor(b5, 32);
        b6 += __shfl_xor(b6, 16); b6 += __shfl_xor(b6, 32);
        b7 += __shfl_xor(b7, 16); b7 += __shfl_xor(b7, 32);
        if (h == 0) {
            uint4 o;
            o.x = ((u32)f2bf(b1) << 16) | f2bf(b0);
            o.y = ((u32)f2bf(b3) << 16) | f2bf(b2);
            o.z = ((u32)f2bf(b5) << 16) | f2bf(b4);
            o.w = ((u32)f2bf(b7) << 16) | f2bf(b6);
            *(uint4*)(X0 + (size_t)row * 320 + 128 + 8 * lc) = o;
        }
    } else {
        float c0 = 0.f, c1 = 0.f, c2 = 0.f, c3 = 0.f;
        int s = rpN[row], e = rpN[row + 1];
        int j = s;
        for (; j + 8 <= e; j += 8) {
            int2 p0 = cvN[j + h], p1 = cvN[j + 4 + h];
            const float* r0 = arcs + (size_t)p0.x * 66 + 2 + 4 * lc;
            const float* r1 = arcs + (size_t)p1.x * 66 + 2 + 4 * lc;
            float2 f0a = *(const float2*)(r0), f0b = *(const float2*)(r0 + 2);
            float2 f1a = *(const float2*)(r1), f1b = *(const float2*)(r1 + 2);
            float v0 = __int_as_float(p0.y), v1 = __int_as_float(p1.y);
            c0 += v0 * f0a.x + v1 * f1a.x;  c1 += v0 * f0a.y + v1 * f1a.y;
            c2 += v0 * f0b.x + v1 * f1b.x;  c3 += v0 * f0b.y + v1 * f1b.y;
        }
        for (; j + 4 <= e; j += 4) {
            int2 pp = cvN[j + h];
            const float* r0 = arcs + (size_t)pp.x * 66 + 2 + 4 * lc;
            float2 fa = *(const float2*)(r0), fb = *(const float2*)(r0 + 2);
            float v = __int_as_float(pp.y);
            c0 += v * fa.x; c1 += v * fa.y; c2 += v * fb.x; c3 += v * fb.y;
        }
        if (h < e - j) {
            int2 pp = cvN[j + h];
            const float* r0 = arcs + (size_t)pp.x * 66 + 2 + 4 * lc;
            float2 fa = *(const float2*)(r0), fb = *(const float2*)(r0 + 2);
            float v = __int_as_float(pp.y);
            c0 += v * fa.x; c1 += v * fa.y; c2 += v * fb.x; c3 += v * fb.y;
        }
        c0 += __shfl_xor(c0, 16); c0 += __shfl_xor(c0, 32);
        c1 += __shfl_xor(c1, 16); c1 += __shfl_xor(c1, 32);
        c2 += __shfl_xor(c2, 16); c2 += __shfl_xor(c2, 32);
        c3 += __shfl_xor(c3, 16); c3 += __shfl_xor(c3, 32);
        if (h == 0) {
            uint2 o;
            o.x = ((u32)f2bf(c1) << 16) | f2bf(c0);
            o.y = ((u32)f2bf(c3) << 16) | f2bf(c2);
            *(uint2*)(X0 + (size_t)row * 320 + 256 + 4 * lc) = o;
        }
    }
}

// ---------------- agg_states spmm (unchanged from benched r6) ----------------

__global__ void k_spmm_state(const int* __restrict__ rp, const int2* __restrict__ cv,
                             const u16* __restrict__ state, u16* agg, int N,
                             const int* __restrict__ anyf, const int* __restrict__ contprev,
                             int* contout) {
    int a = *anyf;
    int p = contprev ? *contprev : 1;
    int c = (a && p) ? 1 : 0;
    if (blockIdx.x == 0 && threadIdx.x == 0) *contout = c;
    if (!c) return;
    int row = blockIdx.x * 4 + (threadIdx.x >> 6);
    if (row >= N) return;
    int l = threadIdx.x & 63;
    int h = l >> 4;        // edge slot 0..3
    int lc = l & 15;       // u16 cols [8lc, 8lc+8)
    float a0 = 0.f, a1 = 0.f, a2 = 0.f, a3 = 0.f;
    float a4 = 0.f, a5 = 0.f, a6 = 0.f, a7 = 0.f;
    int s = rp[row], e = rp[row + 1];
    int j = s;
    for (; j + 16 <= e; j += 16) {
        int2 p0 = cv[j + h],      p1 = cv[j + 4 + h];
        int2 p2 = cv[j + 8 + h],  p3 = cv[j + 12 + h];
        uint4 u0 = *(const uint4*)(state + (size_t)p0.x * 256 + 8 * lc);
        uint4 u1 = *(const uint4*)(state + (size_t)p1.x * 256 + 8 * lc);
        uint4 u2 = *(const uint4*)(state + (size_t)p2.x * 256 + 8 * lc);
        uint4 u3 = *(const uint4*)(state + (size_t)p3.x * 256 + 8 * lc);
        float v0 = __int_as_float(p0.y), v1 = __int_as_float(p1.y);
        float v2 = __int_as_float(p2.y), v3 = __int_as_float(p3.y);
        a0 += v0 * lo16(u0.x) + v1 * lo16(u1.x) + v2 * lo16(u2.x) + v3 * lo16(u3.x);
        a1 += v0 * hi16(u0.x) + v1 * hi16(u1.x) + v2 * hi16(u2.x) + v3 * hi16(u3.x);
        a2 += v0 * lo16(u0.y) + v1 * lo16(u1.y) + v2 * lo16(u2.y) + v3 * lo16(u3.y);
        a3 += v0 * hi16(u0.y) + v1 * hi16(u1.y) + v2 * hi16(u2.y) + v3 * hi16(u3.y);
        a4 += v0 * lo16(u0.z) + v1 * lo16(u1.z) + v2 * lo16(u2.z) + v3 * lo16(u3.z);
        a5 += v0 * hi16(u0.z) + v1 * hi16(u1.z) + v2 * hi16(u2.z) + v3 * hi16(u3.z);
        a6 += v0 * lo16(u0.w) + v1 * lo16(u1.w) + v2 * lo16(u2.w) + v3 * lo16(u3.w);
        a7 += v0 * hi16(u0.w) + v1 * hi16(u1.w) + v2 * hi16(u2.w) + v3 * hi16(u3.w);
    }
    for (; j + 8 <= e; j += 8) {
        int2 p0 = cv[j + h], p1 = cv[j + 4 + h];
        uint4 u0 = *(const uint4*)(state + (size_t)p0.x * 256 + 8 * lc);
        uint4 u1 = *(const uint4*)(state + (size_t)p1.x * 256 + 8 * lc);
        float v0 = __int_as_float(p0.y), v1 = __int_as_float(p1.y);
        a0 += v0 * lo16(u0.x) + v1 * lo16(u1.x);
        a1 += v0 * hi16(u0.x) + v1 * hi16(u1.x);
        a2 += v0 * lo16(u0.y) + v1 * lo16(u1.y);
        a3 += v0 * hi16(u0.y) + v1 * hi16(u1.y);
        a4 += v0 * lo16(u0.z) + v1 * lo16(u1.z);
        a5 += v0 * hi16(u0.z) + v1 * hi16(u1.z);
        a6 += v0 * lo16(u0.w) + v1 * lo16(u1.w);
        a7 += v0 * hi16(u0.w) + v1 * hi16(u1.w);
    }
    for (; j + 4 <= e; j += 4) {
        int2 pp = cv[j + h];
        uint4 u = *(const uint4*)(state + (size_t)pp.x * 256 + 8 * lc);
        float v = __int_as_float(pp.y);
        a0 += v * lo16(u.x); a1 += v * hi16(u.x);
        a2 += v * lo16(u.y); a3 += v * hi16(u.y);
        a4 += v * lo16(u.z); a5 += v * hi16(u.z);
        a6 += v * lo16(u.w); a7 += v * hi16(u.w);
    }
    if (h < e - j) {
        int2 pp = cv[j + h];
        uint4 u = *(const uint4*)(state + (size_t)pp.x * 256 + 8 * lc);
        float v = __int_as_float(pp.y);
        a0 += v * lo16(u.x); a1 += v * hi16(u.x);
        a2 += v * lo16(u.y); a3 += v * hi16(u.y);
        a4 += v * lo16(u.z); a5 += v * hi16(u.z);
        a6 += v * lo16(u.w); a7 += v * hi16(u.w);
    }
    a0 += __shfl_xor(a0, 16); a0 += __shfl_xor(a0, 32);
    a1 += __shfl_xor(a1, 16); a1 += __shfl_xor(a1, 32);
    a2 += __shfl_xor(a2, 16); a2 += __shfl_xor(a2, 32);
    a3 += __shfl_xor(a3, 16); a3 += __shfl_xor(a3, 32);
    a4 += __shfl_xor(a4, 16); a4 += __shfl_xor(a4, 32);
    a5 += __shfl_xor(a5, 16); a5 += __shfl_xor(a5, 32);
    a6 += __shfl_xor(a6, 16); a6 += __shfl_xor(a6, 32);
    a7 += __shfl_xor(a7, 16); a7 += __shfl_xor(a7, 32);
    if (h == 0) {
        uint4 o;
        o.x = ((u32)f2bf(a1) << 16) | f2bf(a0);
        o.y = ((u32)f2bf(a3) << 16) | f2bf(a2);
        o.z = ((u32)f2bf(a5) << 16) | f2bf(a4);
        o.w = ((u32)f2bf(a7) << 16) | f2bf(a6);
        *(uint4*)(agg + (size_t)row * 256 + 8 * lc) = o;
    }
}

// ---------------- convergence check (used once, t=0) ----------------

__global__ void k_check(const u16* __restrict__ cur, const u16* __restrict__ prev,
                        int N, int* anyf) {
    int row = blockIdx.x * 4 + (threadIdx.x >> 6);
    int l = threadIdx.x & 63;
    float d2 = 0.f, n2 = 0.f;
    if (row < N) {
        u32 u1 = *(const u32*)(cur + (size_t)row * 256 + 2 * l);
        u32 u2 = *(const u32*)(prev + (size_t)row * 256 + 2 * l);
        float ax = lo16(u1), ay = hi16(u1);
        float bx = lo16(u2), by = hi16(u2);
        float dx = ax - bx, dy = ay - by;
        d2 = dx * dx + dy * dy;
        n2 = bx * bx + by * by;
    }
    for (int off = 32; off; off >>= 1) {
        d2 += __shfl_down(d2, off);
        n2 += __shfl_down(n2, off);
    }
    if (l == 0 && row < N && d2 > THR2 * n2) {
        volatile int* f = (volatile int*)anyf;
        if (*f == 0) atomicOr(anyf, 1);   // stale-0 read => harmless extra atomic
    }
}

// ---------------- MFMA GEMM: D = epi(A @ BT^T), 128x128 tiles, BK=32 --------------
// (reverted to the r6-measured structure; LDS 17.4KB -> 8 blocks/CU)
// permCD: bit0 = Cadd is in pi-layout (read uint2); bit1 = store D in pi-layout
// (col wn+ni*16+ml stored at wn+ml*4+ni) with uint2 stores. pi is a pure column
// permutation; bias/Cadd slot ni always corresponds to ORIGINAL col n0+wn+ni*16+ml.
// chk path (gemm2) uses permCD=0 (natural layout for state).
// skipmode: 0 = always run, 1 = return if *contflag==0, 2 = copy state if *contflag==0

__global__ __launch_bounds__(256)
void k_gemm(const u16* __restrict__ A, int lda,
            const u16* __restrict__ BT, int ldb,
            const float* __restrict__ bias,
            const u16* __restrict__ Cadd, int ldc,
            u16* __restrict__ D, int ldd,
            int M, int K, int dotanh,
            const int* __restrict__ contflag, int skipmode,
            const u16* __restrict__ copysrc, u16* __restrict__ copydst,
            int* chk, int permCD) {
    int m0 = blockIdx.x * 128;
    int n0 = blockIdx.y * 128;
    if (skipmode && *contflag == 0) {
        if (skipmode == 2) {
            for (int c = threadIdx.x; c < 2048; c += 256) {
                int r = c >> 4, ch = (c & 15) * 8;
                int row = m0 + r;
                if (row < M)
                    *(uint4*)(copydst + (size_t)row * 256 + ch) =
                        *(const uint4*)(copysrc + (size_t)row * 256 + ch);
            }
        }
        return;   // converged: chk stays 0 => stays converged
    }
    __shared__ u16 As[128 * 32];
    __shared__ u16 Bs[128 * 32];
    __shared__ float rsum[256];   // [0..127]=d2, [128..255]=n2
    int tid = threadIdx.x;
    int wave = tid >> 6, l = tid & 63;
    int wm = (wave >> 1) * 64, wn = (wave & 1) * 64;
    int ml = l & 15, kg = l >> 4;
    int ko = kg * 8;
    f32x4 acc[4][4];
#pragma unroll
    for (int mi = 0; mi < 4; ++mi)
#pragma unroll
        for (int ni = 0; ni < 4; ++ni) acc[mi][ni] = (f32x4){0.f, 0.f, 0.f, 0.f};

    if (chk) rsum[tid] = 0.f;

    for (int k0 = 0; k0 < K; k0 += 32) {
#pragma unroll
        for (int i = 0; i < 2; ++i) {
            int c = tid + i * 256;            // chunk 0..511; 16B each
            int r = c >> 2, half = (c & 3) * 8;
            int rowA = m0 + r; rowA = (rowA < M) ? rowA : (M - 1);
            gl_lds16(A + (size_t)rowA * lda + k0 + half, &As[c * 8]);
            gl_lds16(BT + (size_t)(n0 + r) * ldb + k0 + half, &Bs[c * 8]);
        }
        __syncthreads();
        short8 av[4], bv[4];
#pragma unroll
        for (int mi = 0; mi < 4; ++mi)
            av[mi] = *(const short8*)(&As[(wm + mi * 16 + ml) * 32 + ko]);
#pragma unroll
        for (int ni = 0; ni < 4; ++ni)
            bv[ni] = *(const short8*)(&Bs[(wn + ni * 16 + ml) * 32 + ko]);
#pragma unroll
        for (int mi = 0; mi < 4; ++mi)
#pragma unroll
            for (int ni = 0; ni < 4; ++ni)
                acc[mi][ni] = __builtin_amdgcn_mfma_f32_16x16x32_bf16(
                    av[mi], bv[ni], acc[mi][ni], 0, 0, 0);
        __syncthreads();
    }
    // epilogue (mi, r outer so per-row check partials accumulate over ni)
#pragma unroll
    for (int mi = 0; mi < 4; ++mi) {
#pragma unroll
        for (int r = 0; r < 4; ++r) {
            int row = m0 + wm + mi * 16 + kg * 4 + r;
            bool ok = row < M;
            float d2l = 0.f, n2l = 0.f;
            uint2 cb2;
            if (ok && (permCD & 1))
                cb2 = *(const uint2*)(Cadd + (size_t)row * ldc + n0 + wn + ml * 4);
            float vv[4];
#pragma unroll
            for (int ni = 0; ni < 4; ++ni) {
                int col = n0 + wn + ni * 16 + ml;
                float v = acc[mi][ni][r];
                if (bias) v += bias[col];
                if (Cadd) {
                    if (permCD & 1) {
                        u32 w = (ni < 2) ? cb2.x : cb2.y;
                        v += (ni & 1) ? hi16(w) : lo16(w);
                    } else if (ok) {
                        v += bf2f(Cadd[(size_t)row * ldc + col]);
                    }
                }
                if (dotanh) v = tanhf(v);
                vv[ni] = v;
            }
            if (permCD & 2) {
                if (ok) {
                    uint2 o;
                    o.x = ((u32)f2bf(vv[1]) << 16) | f2bf(vv[0]);
                    o.y = ((u32)f2bf(vv[3]) << 16) | f2bf(vv[2]);
                    *(uint2*)(D + (size_t)row * ldd + n0 + wn + ml * 4) = o;
                }
            } else {
#pragma unroll
                for (int ni = 0; ni < 4; ++ni) {
                    int col = n0 + wn + ni * 16 + ml;
                    if (ok) {
                        u16 hb = f2bf(vv[ni]);
                        D[(size_t)row * ldd + col] = hb;
                        if (chk) {
                            float vq = bf2f(hb);
                            float o  = bf2f(copysrc[(size_t)row * 256 + col]);
                            float d = vq - o;
                            d2l += d * d;
                            n2l += o * o;
                        }
                    }
                }
            }
            if (chk) {
#pragma unroll
                for (int off = 1; off < 16; off <<= 1) {
                    d2l += __shfl_xor(d2l, off);
                    n2l += __shfl_xor(n2l, off);
                }
                if (ml == 0) {
                    int lrow = wm + mi * 16 + kg * 4 + r;
                    atomicAdd(&rsum[lrow], d2l);
                    atomicAdd(&rsum[128 + lrow], n2l);
                }
            }
        }
    }
    if (chk) {
        __syncthreads();
        bool viol = false;
        if (tid < 128) {
            int row = m0 + tid;
            if (row < M) viol = rsum[tid] > THR2 * rsum[128 + tid];
        }
        if (__any(viol) && (threadIdx.x & 63) == 0) {
            volatile int* f = (volatile int*)chk;
            if (*f == 0) atomicOr(chk, 1);
        }
    }
}

// ---------------- final tiny-N output GEMM: out = (HO @ Wo2 + bo2) * mask ----------
// HO is in pi-layout: stored col cp holds original col
// (cp & ~63) + (cp&3)*16 + ((cp&63)>>2); weight row index uses the original col.

__global__ void k_out(const u16* __restrict__ HO, const float* __restrict__ Wo2,
                      const float* __restrict__ bo2,
                      const int* __restrict__ m1,
                      const int* __restrict__ m2,
                      float* __restrict__ out, int N) {
    __shared__ float w[512 * 7];
    for (int i = threadIdx.x; i < 512 * 7; i += 256) w[i] = Wo2[i];
    __syncthreads();
    int row = blockIdx.x * 4 + (threadIdx.x >> 6);
    if (row >= N) return;
    int l = threadIdx.x & 63;
    uint4 u = *(const uint4*)(HO + (size_t)row * 512 + l * 8);
    float h[8];
    h[0] = lo16(u.x); h[1] = hi16(u.x);
    h[2] = lo16(u.y); h[3] = hi16(u.y);
    h[4] = lo16(u.z); h[5] = hi16(u.z);
    h[6] = lo16(u.w); h[7] = hi16(u.w);
    float a[7] = {0.f, 0.f, 0.f, 0.f, 0.f, 0.f, 0.f};
#pragma unroll
    for (int i = 0; i < 8; ++i) {
        int cp = l * 8 + i;
        int q = cp & 63;
        int orig = (cp & ~63) + ((q & 3) << 4) + (q >> 2);   // pi^-1
        int base = orig * 7;
#pragma unroll
        for (int j = 0; j < 7; ++j) a[j] += h[i] * w[base + j];
    }
    for (int off = 32; off; off >>= 1) {
#pragma unroll
        for (int j = 0; j < 7; ++j) a[j] += __shfl_down(a[j], off);
    }
    if (l == 0) {
        float mm = (m1[row] != 0 && m2[row] != 0) ? 1.f : 0.f;
#pragma unroll
        for (int j = 0; j < 7; ++j) out[(size_t)row * 7 + j] = (a[j] + bo2[j]) * mm;
    }
}

// ---------------- launch ----------------

extern "C" void kernel_launch(void* const* d_in, const int* in_sizes, int n_in,
                              void* d_out, int out_size, void* d_ws, size_t ws_size,
                              hipStream_t stream) {
    const float* nodes   = (const float*)d_in[0];
    const float* arcs    = (const float*)d_in[1];
    const int*   set_mask    = (const int*)d_in[2];
    const int*   output_mask = (const int*)d_in[3];
    const int*   adj_src = (const int*)d_in[4];
    const int*   adj_dst = (const int*)d_in[5];
    const float* adj_vals= (const float*)d_in[6];
    const int*   an_dst  = (const int*)d_in[7];
    const float* an_vals = (const float*)d_in[8];
    const float* state_init = (const float*)d_in[9];
    const float* Ws1 = (const float*)d_in[10];
    const float* bs1 = (const float*)d_in[11];
    const float* Ws2 = (const float*)d_in[12];
    const float* bs2 = (const float*)d_in[13];
    const float* Wo1 = (const float*)d_in[14];
    const float* bo1 = (const float*)d_in[15];
    const float* Wo2 = (const float*)d_in[16];
    const float* bo2 = (const float*)d_in[17];
    float* out = (float*)d_out;

    const int N = in_sizes[2];     // 50000
    const int E = in_sizes[4];     // 640000

    char* ws = (char*)d_ws;
    size_t off = 0;
    auto alloc = [&](size_t bytes) {
        char* p = ws + off;
        off += (bytes + 255) & ~(size_t)255;
        return p;
    };
    u16* SA0 = (u16*)alloc((size_t)N * 256 * 2);
    u16* SA1 = (u16*)alloc((size_t)N * 256 * 2);
    u16* SA2 = (u16*)alloc((size_t)N * 256 * 2);
    u16* CB  = (u16*)alloc((size_t)N * 512 * 2);
    u16* HID = (u16*)alloc((size_t)N * 512 * 2);
    u16* X0  = HID;                 // X0 (N x 320) aliases HID; consumed before HID first write
    u16* FA  = SA0;                 // final [state|nodes] aliases SA0 (free after iter 9)
    u16* W1selT  = (u16*)alloc(512 * 256 * 2);
    u16* W1baseT = (u16*)alloc(512 * 320 * 2);
    u16* W2T     = (u16*)alloc(128 * 512 * 2);
    u16* Wo1T    = (u16*)alloc(512 * 256 * 2);
    int* rpA  = (int*)alloc((size_t)(N + 1) * 4);
    int* curA = (int*)alloc((size_t)N * 4);
    int* cntA = (int*)alloc((size_t)N * 4);
    int2* cvA = (int2*)alloc((size_t)E * 8);
    int* rpN  = (int*)alloc((size_t)(N + 1) * 4);
    int* curN = (int*)alloc((size_t)N * 4);
    int* cntN = (int*)alloc((size_t)N * 4);
    int2* cvN = (int2*)alloc((size_t)E * 8);
    int* bsA = (int*)alloc(256 * 4);
    int* bsN = (int*)alloc(256 * 4);
    int* flags = (int*)alloc(64 * 4);
    int* anyf = flags;          // [0..10]
    int* cont = flags + 16;     // [0..9]
    (void)ws_size; (void)n_in; (void)out_size;

    const int nb = (N + 255) / 256;
    const int gE = (E + 255) / 256;
    const int gRow = (N + 3) / 4;
    const int gx = (N + 127) / 128;

    // init + CSR build
    k_zero2<<<nb, 256, 0, stream>>>(cntA, cntN, N, flags);
    k_hist2<<<gE, 256, 0, stream>>>(adj_dst, an_dst, cntA, cntN, E);
    k_scan_p1<<<nb, 256, 0, stream>>>(cntA, bsA, N);
    k_scan_p2<<<1, 64, 0, stream>>>(bsA, nb, rpA, N);
    k_scan_p3<<<nb, 256, 0, stream>>>(cntA, bsA, rpA, curA, N);
    k_scan_p1<<<nb, 256, 0, stream>>>(cntN, bsN, N);
    k_scan_p2<<<1, 64, 0, stream>>>(bsN, nb, rpN, N);
    k_scan_p3<<<nb, 256, 0, stream>>>(cntN, bsN, rpN, curN, N);
    k_fill2<<<gE, 256, 0, stream>>>(adj_src, adj_dst, adj_vals, curA, cvA,
                                    an_dst, an_vals, curN, cvN, E);
    // merged weight packing (491520 elems)
    k_pack_all<<<1920, 256, 0, stream>>>(Ws1, Ws2, Wo1, W1selT, W1baseT, W2T, Wo1T);
    // merged conversions (3 * N*32 elems)
    k_conv_all<<<(3 * N * 32 + 255) / 256, 256, 0, stream>>>(nodes, state_init,
                                                             X0, SA0, SA2, N);
    // constant aggregations (fused: y=0 nodes, y=1 arcs)
    k_agg_const<<<dim3(gRow, 2), 256, 0, stream>>>(rpA, cvA, nodes,
                                                   rpN, cvN, arcs, X0, N);
    // C_base = X0 @ W1baseT^T + bs1   (no tanh; pi-layout store)
    k_gemm<<<dim3(gx, 4), 256, 0, stream>>>(X0, 320, W1baseT, 320, bs1,
                                            nullptr, 0, CB, 512, N, 320, 0,
                                            nullptr, 0, nullptr, nullptr, nullptr, 2);
    // 10 unrolled fixed-point iterations
    u16* SAs[3] = {SA0, SA1, SA2};
    for (int t = 0; t < 10; ++t) {
        u16* curS = SAs[t % 3];
        u16* prvS = SAs[(t + 2) % 3];
        u16* nxtS = SAs[(t + 1) % 3];
        if (t == 0)
            k_check<<<gRow, 256, 0, stream>>>(curS, prvS, N, anyf);
        // (for t>=1, anyf[t] was produced by the previous gemm2's fused check)
        k_spmm_state<<<gRow, 256, 0, stream>>>(rpA, cvA, curS, curS + 128, N,
                                               anyf + t, t ? (cont + t - 1) : nullptr,
                                               cont + t);
        // HID = tanh([state|agg] @ W1selT^T + C_base)   (pi-read CB, pi-store HID)
        k_gemm<<<dim3(gx, 4), 256, 0, stream>>>(curS, 256, W1selT, 256, nullptr,
                                                CB, 512, HID, 512, N, 256, 1,
                                                cont + t, 1, nullptr, nullptr,
                                                nullptr, 3);
        // next_state = tanh(HID @ W2T'^T + bs2); copy state if converged;
        // fused: anyf[t+1] = any(||next-cur||^2 > THR2*||cur||^2). W2T' has pi on k.
        k_gemm<<<dim3(gx, 1), 256, 0, stream>>>(HID, 512, W2T, 512, bs2,
                                                nullptr, 0, nxtS, 256, N, 512, 1,
                                                cont + t, 2, curS, nxtS,
                                                anyf + t + 1, 0);
    }
    // final state is in SAs[10 % 3] = SA1
    k_build_fa<<<(N * 64 + 255) / 256, 256, 0, stream>>>(SA1, nodes, FA, N);
    k_gemm<<<dim3(gx, 4), 256, 0, stream>>>(FA, 256, Wo1T, 256, bo1,
                                            nullptr, 0, HID, 512, N, 256, 1,
                                            nullptr, 0, nullptr, nullptr, nullptr, 2);
    k_out<<<gRow, 256, 0, stream>>>(HID, Wo2, bo2, set_mask, output_mask, out, N);
}

// Round 10
// 1985.803 us; speedup vs baseline: 1.3889x; 1.2269x over previous
//
#include <hip/hip_runtime.h>

typedef unsigned short u16;
typedef unsigned int u32;
typedef __attribute__((ext_vector_type(8))) short short8;
typedef __attribute__((ext_vector_type(4))) float f32x4;

#define THR2 1e-4f   // THR^2, THR=0.01
#define CPAD 16      // cur-counter pad (ints): 64B to split atomic cachelines

__device__ __forceinline__ u16 f2bf(float f) {
    u32 u = __float_as_uint(f);
    u32 r = u + 0x7fffu + ((u >> 16) & 1u);   // round-to-nearest-even
    return (u16)(r >> 16);
}
__device__ __forceinline__ float bf2f(u16 h) { return __uint_as_float(((u32)h) << 16); }
__device__ __forceinline__ float lo16(u32 u) { return __uint_as_float(u << 16); }
__device__ __forceinline__ float hi16(u32 u) { return __uint_as_float(u & 0xffff0000u); }

// async global->LDS, 16B per lane. LDS dest must be wave-uniform base + lane*16.
__device__ __forceinline__ void gl_lds16(const u16* g, u16* l) {
    __builtin_amdgcn_global_load_lds(
        (const __attribute__((address_space(1))) void*)g,
        (__attribute__((address_space(3))) void*)l, 16, 0, 0);
}

// ---------------- small init / CSR-build kernels ----------------

__global__ void k_zero2(int* a, int* b, int n, int* flags) {
    int i = blockIdx.x * 256 + threadIdx.x;
    if (blockIdx.x == 0 && threadIdx.x < 64) flags[threadIdx.x] = 0;
    if (i < n) { a[i] = 0; b[i] = 0; }
}

__global__ void k_hist2(const int* __restrict__ adst, const int* __restrict__ ndst,
                        int* ca, int* cn, int E) {
    int e = blockIdx.x * 256 + threadIdx.x;
    if (e < E) {
        atomicAdd(&ca[adst[e]], 1);
        atomicAdd(&cn[ndst[e]], 1);
    }
}

__global__ void k_scan_p1(const int* __restrict__ cnt, int* bs, int n) {
    __shared__ int s[256];
    int i = blockIdx.x * 256 + threadIdx.x;
    s[threadIdx.x] = (i < n) ? cnt[i] : 0;
    __syncthreads();
    for (int off = 128; off > 0; off >>= 1) {
        if (threadIdx.x < off) s[threadIdx.x] += s[threadIdx.x + off];
        __syncthreads();
    }
    if (threadIdx.x == 0) bs[blockIdx.x] = s[0];
}

__global__ void k_scan_p2(int* bs, int nb, int* rp, int n) {
    if (threadIdx.x == 0 && blockIdx.x == 0) {
        int run = 0;
        for (int b = 0; b < nb; ++b) { int t = bs[b]; bs[b] = run; run += t; }
        rp[n] = run;
    }
}

// cur written PADDED (stride CPAD ints)
__global__ void k_scan_p3(const int* __restrict__ cnt, const int* __restrict__ bs,
                          int* rp, int* cur, int n) {
    __shared__ int s[256];
    int i = blockIdx.x * 256 + threadIdx.x;
    int v = (i < n) ? cnt[i] : 0;
    s[threadIdx.x] = v;
    __syncthreads();
    for (int off = 1; off < 256; off <<= 1) {
        int t = (threadIdx.x >= off) ? s[threadIdx.x - off] : 0;
        __syncthreads();
        s[threadIdx.x] += t;
        __syncthreads();
    }
    int excl = s[threadIdx.x] - v + bs[blockIdx.x];
    if (i < n) { rp[i] = excl; cur[(size_t)i * CPAD] = excl; }
}

// CSR fill with PACKED (col,val) payload; padded cur counters
__global__ void k_fill2(const int* __restrict__ asrc, const int* __restrict__ adst,
                        const float* __restrict__ avals,
                        int* curA, int2* __restrict__ cvA,
                        const int* __restrict__ ndst, const float* __restrict__ nvals,
                        int* curN, int2* __restrict__ cvN, int E) {
    int e = blockIdx.x * 256 + threadIdx.x;
    if (e < E) {
        int p = atomicAdd(&curA[(size_t)adst[e] * CPAD], 1);
        long long pa = ((long long)__float_as_int(avals[e]) << 32) | (u32)asrc[e];
        __builtin_nontemporal_store(pa, (long long*)(cvA + p));
        int q = atomicAdd(&curN[(size_t)ndst[e] * CPAD], 1);
        long long pn = ((long long)__float_as_int(nvals[e]) << 32) | (u32)e;
        __builtin_nontemporal_store(pn, (long long*)(cvN + q));
    }
}

// ---------------- merged weight packing (fp32 -> bf16, transposed to [N][K]) --------
// ranges: [0,131072) W1sel | [131072,294912) W1base | [294912,360448) W2 | [360448,491520) Wo1
// W2T k-dim uses the fragment permutation pi: stored k' holds original
// k = (k' & ~63) + (k'&3)*16 + ((k'&63)>>2)   (matches pi-layout HID).

__global__ void k_pack_all(const float* __restrict__ Ws1, const float* __restrict__ Ws2,
                           const float* __restrict__ Wo1,
                           u16* W1selT, u16* W1baseT, u16* W2T, u16* Wo1T) {
    int i = blockIdx.x * 256 + threadIdx.x;
    if (i < 131072) {
        int n = i >> 8, k = i & 255;
        int r = (k < 128) ? k : k + 128;
        W1selT[i] = f2bf(Ws1[r * 512 + n]);
    } else if (i < 294912) {
        int t = i - 131072;
        int n = t / 320, k = t % 320;
        int r = (k < 128) ? (k + 128) : (k + 256);
        W1baseT[t] = f2bf(Ws1[r * 512 + n]);
    } else if (i < 360448) {
        int t = i - 294912;
        int n = t >> 9, kp = t & 511;
        int q = kp & 63;
        int k = (kp & ~63) + ((q & 3) << 4) + (q >> 2);   // pi^-1
        W2T[t] = f2bf(Ws2[k * 128 + n]);
    } else if (i < 491520) {
        int t = i - 360448;
        int n = t >> 8, k = t & 255;
        Wo1T[t] = f2bf(Wo1[k * 512 + n]);
    }
}

// ---------------- merged conversions: X0 nodes-cols, SA0 from state_init, SA2 ones ----

__global__ void k_conv_all(const float* __restrict__ nodes, const float* __restrict__ st,
                           u16* X0, u16* SA0, u16* SA2, int N) {
    int i = blockIdx.x * 256 + threadIdx.x;
    int total = N * 32;
    if (i < total) {
        int r = i >> 5, c4 = i & 31;
        float4 f = *(const float4*)(nodes + (size_t)r * 128 + c4 * 4);
        uint2 o;
        o.x = ((u32)f2bf(f.y) << 16) | f2bf(f.x);
        o.y = ((u32)f2bf(f.w) << 16) | f2bf(f.z);
        *(uint2*)(X0 + (size_t)r * 320 + c4 * 4) = o;
    } else if (i < 2 * total) {
        int t = i - total;
        int r = t >> 5, c4 = t & 31;
        float4 f = *(const float4*)(st + (size_t)r * 128 + c4 * 4);
        uint2 o;
        o.x = ((u32)f2bf(f.y) << 16) | f2bf(f.x);
        o.y = ((u32)f2bf(f.w) << 16) | f2bf(f.z);
        *(uint2*)(SA0 + (size_t)r * 256 + c4 * 4) = o;
    } else if (i < 3 * total) {
        int t = i - 2 * total;
        int r = t >> 5, c4 = t & 31;
        uint2 o; o.x = 0x3f803f80u; o.y = 0x3f803f80u;
        *(uint2*)(SA2 + (size_t)r * 256 + c4 * 4) = o;
    }
}

__global__ void k_build_fa(const u16* __restrict__ SA1, const float* __restrict__ nodes,
                           u16* FA, int N) {
    int i = blockIdx.x * 256 + threadIdx.x;   // N*64
    if (i >= N * 64) return;
    int r = i >> 6, c = i & 63;
    if (c < 32) {
        uint2 o = *(const uint2*)(SA1 + (size_t)r * 256 + c * 4);
        *(uint2*)(FA + (size_t)r * 256 + c * 4) = o;
    } else {
        float4 f = *(const float4*)(nodes + (size_t)r * 128 + (c - 32) * 4);
        uint2 o;
        o.x = ((u32)f2bf(f.y) << 16) | f2bf(f.x);
        o.y = ((u32)f2bf(f.w) << 16) | f2bf(f.z);
        *(uint2*)(FA + (size_t)r * 256 + c * 4) = o;
    }
}

// ---------------- constant aggregations (unchanged from benched r6) ----------------

__global__ void k_agg_const(const int* __restrict__ rpA, const int2* __restrict__ cvA,
                            const float* __restrict__ nodes,
                            const int* __restrict__ rpN, const int2* __restrict__ cvN,
                            const float* __restrict__ arcs,
                            u16* X0, int N) {
    int row = blockIdx.x * 4 + (threadIdx.x >> 6);
    if (row >= N) return;
    int l = threadIdx.x & 63;
    int h = l >> 4;        // edge slot 0..3
    int lc = l & 15;       // column lane-group index
    if (blockIdx.y == 0) {
        float b0 = 0.f, b1 = 0.f, b2 = 0.f, b3 = 0.f;
        float b4 = 0.f, b5 = 0.f, b6 = 0.f, b7 = 0.f;
        int s = rpA[row], e = rpA[row + 1];
        int j = s;
        for (; j + 8 <= e; j += 8) {
            int2 p0 = cvA[j + h], p1 = cvA[j + 4 + h];
            const float* r0 = nodes + (size_t)p0.x * 128 + 8 * lc;
            const float* r1 = nodes + (size_t)p1.x * 128 + 8 * lc;
            float4 f0a = *(const float4*)(r0), f0b = *(const float4*)(r0 + 4);
            float4 f1a = *(const float4*)(r1), f1b = *(const float4*)(r1 + 4);
            float v0 = __int_as_float(p0.y), v1 = __int_as_float(p1.y);
            b0 += v0 * f0a.x + v1 * f1a.x;  b1 += v0 * f0a.y + v1 * f1a.y;
            b2 += v0 * f0a.z + v1 * f1a.z;  b3 += v0 * f0a.w + v1 * f1a.w;
            b4 += v0 * f0b.x + v1 * f1b.x;  b5 += v0 * f0b.y + v1 * f1b.y;
            b6 += v0 * f0b.z + v1 * f1b.z;  b7 += v0 * f0b.w + v1 * f1b.w;
        }
        for (; j + 4 <= e; j += 4) {
            int2 pp = cvA[j + h];
            const float* r0 = nodes + (size_t)pp.x * 128 + 8 * lc;
            float4 fa = *(const float4*)(r0), fb = *(const float4*)(r0 + 4);
            float v = __int_as_float(pp.y);
            b0 += v * fa.x; b1 += v * fa.y; b2 += v * fa.z; b3 += v * fa.w;
            b4 += v * fb.x; b5 += v * fb.y; b6 += v * fb.z; b7 += v * fb.w;
        }
        if (h < e - j) {
            int2 pp = cvA[j + h];
            const float* r0 = nodes + (size_t)pp.x * 128 + 8 * lc;
            float4 fa = *(const float4*)(r0), fb = *(const float4*)(r0 + 4);
            float v = __int_as_float(pp.y);
            b0 += v * fa.x; b1 += v * fa.y; b2 += v * fa.z; b3 += v * fa.w;
            b4 += v * fb.x; b5 += v * fb.y; b6 += v * fb.z; b7 += v * fb.w;
        }
        b0 += __shfl_xor(b0, 16); b0 += __shfl_xor(b0, 32);
        b1 += __shfl_xor(b1, 16); b1 += __shfl_xor(b1, 32);
        b2 += __shfl_xor(b2, 16); b2 += __shfl_xor(b2, 32);
        b3 += __shfl_xor(b3, 16); b3 += __shfl_xor(b3, 32);
        b4 += __shfl_xor(b4, 16); b4 += __shfl_xor(b4, 32);
        b5 += __shfl_xor(b5, 16); b5 += __shfl_xor(b5, 32);
        b6 += __shfl_xor(b6, 16); b6 += __shfl_xor(b6, 32);
        b7 += __shfl_xor(b7, 16); b7 += __shfl_xor(b7, 32);
        if (h == 0) {
            uint4 o;
            o.x = ((u32)f2bf(b1) << 16) | f2bf(b0);
            o.y = ((u32)f2bf(b3) << 16) | f2bf(b2);
            o.z = ((u32)f2bf(b5) << 16) | f2bf(b4);
            o.w = ((u32)f2bf(b7) << 16) | f2bf(b6);
            *(uint4*)(X0 + (size_t)row * 320 + 128 + 8 * lc) = o;
        }
    } else {
        float c0 = 0.f, c1 = 0.f, c2 = 0.f, c3 = 0.f;
        int s = rpN[row], e = rpN[row + 1];
        int j = s;
        for (; j + 8 <= e; j += 8) {
            int2 p0 = cvN[j + h], p1 = cvN[j + 4 + h];
            const float* r0 = arcs + (size_t)p0.x * 66 + 2 + 4 * lc;
            const float* r1 = arcs + (size_t)p1.x * 66 + 2 + 4 * lc;
            float2 f0a = *(const float2*)(r0), f0b = *(const float2*)(r0 + 2);
            float2 f1a = *(const float2*)(r1), f1b = *(const float2*)(r1 + 2);
            float v0 = __int_as_float(p0.y), v1 = __int_as_float(p1.y);
            c0 += v0 * f0a.x + v1 * f1a.x;  c1 += v0 * f0a.y + v1 * f1a.y;
            c2 += v0 * f0b.x + v1 * f1b.x;  c3 += v0 * f0b.y + v1 * f1b.y;
        }
        for (; j + 4 <= e; j += 4) {
            int2 pp = cvN[j + h];
            const float* r0 = arcs + (size_t)pp.x * 66 + 2 + 4 * lc;
            float2 fa = *(const float2*)(r0), fb = *(const float2*)(r0 + 2);
            float v = __int_as_float(pp.y);
            c0 += v * fa.x; c1 += v * fa.y; c2 += v * fb.x; c3 += v * fb.y;
        }
        if (h < e - j) {
            int2 pp = cvN[j + h];
            const float* r0 = arcs + (size_t)pp.x * 66 + 2 + 4 * lc;
            float2 fa = *(const float2*)(r0), fb = *(const float2*)(r0 + 2);
            float v = __int_as_float(pp.y);
            c0 += v * fa.x; c1 += v * fa.y; c2 += v * fb.x; c3 += v * fb.y;
        }
        c0 += __shfl_xor(c0, 16); c0 += __shfl_xor(c0, 32);
        c1 += __shfl_xor(c1, 16); c1 += __shfl_xor(c1, 32);
        c2 += __shfl_xor(c2, 16); c2 += __shfl_xor(c2, 32);
        c3 += __shfl_xor(c3, 16); c3 += __shfl_xor(c3, 32);
        if (h == 0) {
            uint2 o;
            o.x = ((u32)f2bf(c1) << 16) | f2bf(c0);
            o.y = ((u32)f2bf(c3) << 16) | f2bf(c2);
            *(uint2*)(X0 + (size_t)row * 320 + 256 + 4 * lc) = o;
        }
    }
}

// ---------------- agg_states spmm (unchanged from benched r6) ----------------

__global__ void k_spmm_state(const int* __restrict__ rp, const int2* __restrict__ cv,
                             const u16* __restrict__ state, u16* agg, int N,
                             const int* __restrict__ anyf, const int* __restrict__ contprev,
                             int* contout) {
    int a = *anyf;
    int p = contprev ? *contprev : 1;
    int c = (a && p) ? 1 : 0;
    if (blockIdx.x == 0 && threadIdx.x == 0) *contout = c;
    if (!c) return;
    int row = blockIdx.x * 4 + (threadIdx.x >> 6);
    if (row >= N) return;
    int l = threadIdx.x & 63;
    int h = l >> 4;        // edge slot 0..3
    int lc = l & 15;       // u16 cols [8lc, 8lc+8)
    float a0 = 0.f, a1 = 0.f, a2 = 0.f, a3 = 0.f;
    float a4 = 0.f, a5 = 0.f, a6 = 0.f, a7 = 0.f;
    int s = rp[row], e = rp[row + 1];
    int j = s;
    for (; j + 16 <= e; j += 16) {
        int2 p0 = cv[j + h],      p1 = cv[j + 4 + h];
        int2 p2 = cv[j + 8 + h],  p3 = cv[j + 12 + h];
        uint4 u0 = *(const uint4*)(state + (size_t)p0.x * 256 + 8 * lc);
        uint4 u1 = *(const uint4*)(state + (size_t)p1.x * 256 + 8 * lc);
        uint4 u2 = *(const uint4*)(state + (size_t)p2.x * 256 + 8 * lc);
        uint4 u3 = *(const uint4*)(state + (size_t)p3.x * 256 + 8 * lc);
        float v0 = __int_as_float(p0.y), v1 = __int_as_float(p1.y);
        float v2 = __int_as_float(p2.y), v3 = __int_as_float(p3.y);
        a0 += v0 * lo16(u0.x) + v1 * lo16(u1.x) + v2 * lo16(u2.x) + v3 * lo16(u3.x);
        a1 += v0 * hi16(u0.x) + v1 * hi16(u1.x) + v2 * hi16(u2.x) + v3 * hi16(u3.x);
        a2 += v0 * lo16(u0.y) + v1 * lo16(u1.y) + v2 * lo16(u2.y) + v3 * lo16(u3.y);
        a3 += v0 * hi16(u0.y) + v1 * hi16(u1.y) + v2 * hi16(u2.y) + v3 * hi16(u3.y);
        a4 += v0 * lo16(u0.z) + v1 * lo16(u1.z) + v2 * lo16(u2.z) + v3 * lo16(u3.z);
        a5 += v0 * hi16(u0.z) + v1 * hi16(u1.z) + v2 * hi16(u2.z) + v3 * hi16(u3.z);
        a6 += v0 * lo16(u0.w) + v1 * lo16(u1.w) + v2 * lo16(u2.w) + v3 * lo16(u3.w);
        a7 += v0 * hi16(u0.w) + v1 * hi16(u1.w) + v2 * hi16(u2.w) + v3 * hi16(u3.w);
    }
    for (; j + 8 <= e; j += 8) {
        int2 p0 = cv[j + h], p1 = cv[j + 4 + h];
        uint4 u0 = *(const uint4*)(state + (size_t)p0.x * 256 + 8 * lc);
        uint4 u1 = *(const uint4*)(state + (size_t)p1.x * 256 + 8 * lc);
        float v0 = __int_as_float(p0.y), v1 = __int_as_float(p1.y);
        a0 += v0 * lo16(u0.x) + v1 * lo16(u1.x);
        a1 += v0 * hi16(u0.x) + v1 * hi16(u1.x);
        a2 += v0 * lo16(u0.y) + v1 * lo16(u1.y);
        a3 += v0 * hi16(u0.y) + v1 * hi16(u1.y);
        a4 += v0 * lo16(u0.z) + v1 * lo16(u1.z);
        a5 += v0 * hi16(u0.z) + v1 * hi16(u1.z);
        a6 += v0 * lo16(u0.w) + v1 * lo16(u1.w);
        a7 += v0 * hi16(u0.w) + v1 * hi16(u1.w);
    }
    for (; j + 4 <= e; j += 4) {
        int2 pp = cv[j + h];
        uint4 u = *(const uint4*)(state + (size_t)pp.x * 256 + 8 * lc);
        float v = __int_as_float(pp.y);
        a0 += v * lo16(u.x); a1 += v * hi16(u.x);
        a2 += v * lo16(u.y); a3 += v * hi16(u.y);
        a4 += v * lo16(u.z); a5 += v * hi16(u.z);
        a6 += v * lo16(u.w); a7 += v * hi16(u.w);
    }
    if (h < e - j) {
        int2 pp = cv[j + h];
        uint4 u = *(const uint4*)(state + (size_t)pp.x * 256 + 8 * lc);
        float v = __int_as_float(pp.y);
        a0 += v * lo16(u.x); a1 += v * hi16(u.x);
        a2 += v * lo16(u.y); a3 += v * hi16(u.y);
        a4 += v * lo16(u.z); a5 += v * hi16(u.z);
        a6 += v * lo16(u.w); a7 += v * hi16(u.w);
    }
    a0 += __shfl_xor(a0, 16); a0 += __shfl_xor(a0, 32);
    a1 += __shfl_xor(a1, 16); a1 += __shfl_xor(a1, 32);
    a2 += __shfl_xor(a2, 16); a2 += __shfl_xor(a2, 32);
    a3 += __shfl_xor(a3, 16); a3 += __shfl_xor(a3, 32);
    a4 += __shfl_xor(a4, 16); a4 += __shfl_xor(a4, 32);
    a5 += __shfl_xor(a5, 16); a5 += __shfl_xor(a5, 32);
    a6 += __shfl_xor(a6, 16); a6 += __shfl_xor(a6, 32);
    a7 += __shfl_xor(a7, 16); a7 += __shfl_xor(a7, 32);
    if (h == 0) {
        uint4 o;
        o.x = ((u32)f2bf(a1) << 16) | f2bf(a0);
        o.y = ((u32)f2bf(a3) << 16) | f2bf(a2);
        o.z = ((u32)f2bf(a5) << 16) | f2bf(a4);
        o.w = ((u32)f2bf(a7) << 16) | f2bf(a6);
        *(uint4*)(agg + (size_t)row * 256 + 8 * lc) = o;
    }
}

// ---------------- convergence check (used once, t=0) ----------------

__global__ void k_check(const u16* __restrict__ cur, const u16* __restrict__ prev,
                        int N, int* anyf) {
    int row = blockIdx.x * 4 + (threadIdx.x >> 6);
    int l = threadIdx.x & 63;
    float d2 = 0.f, n2 = 0.f;
    if (row < N) {
        u32 u1 = *(const u32*)(cur + (size_t)row * 256 + 2 * l);
        u32 u2 = *(const u32*)(prev + (size_t)row * 256 + 2 * l);
        float ax = lo16(u1), ay = hi16(u1);
        float bx = lo16(u2), by = hi16(u2);
        float dx = ax - bx, dy = ay - by;
        d2 = dx * dx + dy * dy;
        n2 = bx * bx + by * by;
    }
    for (int off = 32; off; off >>= 1) {
        d2 += __shfl_down(d2, off);
        n2 += __shfl_down(n2, off);
    }
    if (l == 0 && row < N && d2 > THR2 * n2) {
        volatile int* f = (volatile int*)anyf;
        if (*f == 0) atomicOr(anyf, 1);   // stale-0 read => harmless extra atomic
    }
}

// ---------------- MFMA GEMM: D = epi(A @ BT^T), 64x128 tiles, BK=32 --------------
// 64-row M-tile (halved vs r9): doubles block count -> fixes tail quantization
// (gemm1 1564->3128 blocks, gemm2 391->782). Wave w owns rows [16w,16w+16),
// all 128 cols (acc[8]). Same per-element K-order as the 128-tile version =>
// bit-identical numerics. LDS 12.5KB.
// permCD: bit0 = Cadd in pi-layout (uint2 reads); bit1 = store D in pi-layout
// (col 64g + j*16 + ml stored at 64g + ml*4 + j) with uint2 stores.
// chk path (gemm2) uses permCD=0. skipmode: 0=run, 1=return if conv, 2=copy state.

__global__ __launch_bounds__(256)
void k_gemm(const u16* __restrict__ A, int lda,
            const u16* __restrict__ BT, int ldb,
            const float* __restrict__ bias,
            const u16* __restrict__ Cadd, int ldc,
            u16* __restrict__ D, int ldd,
            int M, int K, int dotanh,
            const int* __restrict__ contflag, int skipmode,
            const u16* __restrict__ copysrc, u16* __restrict__ copydst,
            int* chk, int permCD) {
    int m0 = blockIdx.x * 64;
    int n0 = blockIdx.y * 128;
    if (skipmode && *contflag == 0) {
        if (skipmode == 2) {
            for (int c = threadIdx.x; c < 1024; c += 256) {
                int r = c >> 4, ch = (c & 15) * 8;
                int row = m0 + r;
                if (row < M)
                    *(uint4*)(copydst + (size_t)row * 256 + ch) =
                        *(const uint4*)(copysrc + (size_t)row * 256 + ch);
            }
        }
        return;   // converged: chk stays 0 => stays converged
    }
    __shared__ u16 As[64 * 32];
    __shared__ u16 Bs[128 * 32];
    __shared__ float rsum[128];   // [0..63]=d2, [64..127]=n2
    int tid = threadIdx.x;
    int wave = tid >> 6, l = tid & 63;
    int wm = wave * 16;
    int ml = l & 15, kg = l >> 4;
    int ko = kg * 8;
    f32x4 acc[8];
#pragma unroll
    for (int ni = 0; ni < 8; ++ni) acc[ni] = (f32x4){0.f, 0.f, 0.f, 0.f};

    if (chk && tid < 128) rsum[tid] = 0.f;

    for (int k0 = 0; k0 < K; k0 += 32) {
        {   // As: 64x32 = 256 chunks, 1/thread
            int c = tid;
            int r = c >> 2, half = (c & 3) * 8;
            int rowA = m0 + r; rowA = (rowA < M) ? rowA : (M - 1);
            gl_lds16(A + (size_t)rowA * lda + k0 + half, &As[c * 8]);
        }
#pragma unroll
        for (int i = 0; i < 2; ++i) {   // Bs: 128x32 = 512 chunks, 2/thread
            int c = tid + i * 256;
            int r = c >> 2, half = (c & 3) * 8;
            gl_lds16(BT + (size_t)(n0 + r) * ldb + k0 + half, &Bs[c * 8]);
        }
        __syncthreads();
        short8 av = *(const short8*)(&As[(wm + ml) * 32 + ko]);
        short8 bv[8];
#pragma unroll
        for (int ni = 0; ni < 8; ++ni)
            bv[ni] = *(const short8*)(&Bs[(ni * 16 + ml) * 32 + ko]);
#pragma unroll
        for (int ni = 0; ni < 8; ++ni)
            acc[ni] = __builtin_amdgcn_mfma_f32_16x16x32_bf16(
                av, bv[ni], acc[ni], 0, 0, 0);
        __syncthreads();
    }
    // epilogue
#pragma unroll
    for (int r = 0; r < 4; ++r) {
        int lrow = wm + kg * 4 + r;
        int row = m0 + lrow;
        bool ok = row < M;
        float d2l = 0.f, n2l = 0.f;
        float vv[8];
        uint2 cb2[2];
        if (ok && (permCD & 1)) {
            cb2[0] = *(const uint2*)(Cadd + (size_t)row * ldc + n0 + ml * 4);
            cb2[1] = *(const uint2*)(Cadd + (size_t)row * ldc + n0 + 64 + ml * 4);
        }
#pragma unroll
        for (int ni = 0; ni < 8; ++ni) {
            int col = n0 + ni * 16 + ml;
            float v = acc[ni][r];
            if (bias) v += bias[col];
            if (Cadd) {
                if (permCD & 1) {
                    int g = ni >> 2, j = ni & 3;
                    u32 w = (j < 2) ? cb2[g].x : cb2[g].y;
                    v += (j & 1) ? hi16(w) : lo16(w);
                } else if (ok) {
                    v += bf2f(Cadd[(size_t)row * ldc + col]);
                }
            }
            if (dotanh) v = tanhf(v);
            vv[ni] = v;
        }
        if (permCD & 2) {
            if (ok) {
                uint2 o0, o1;
                o0.x = ((u32)f2bf(vv[1]) << 16) | f2bf(vv[0]);
                o0.y = ((u32)f2bf(vv[3]) << 16) | f2bf(vv[2]);
                o1.x = ((u32)f2bf(vv[5]) << 16) | f2bf(vv[4]);
                o1.y = ((u32)f2bf(vv[7]) << 16) | f2bf(vv[6]);
                *(uint2*)(D + (size_t)row * ldd + n0 + ml * 4) = o0;
                *(uint2*)(D + (size_t)row * ldd + n0 + 64 + ml * 4) = o1;
            }
        } else {
#pragma unroll
            for (int ni = 0; ni < 8; ++ni) {
                int col = n0 + ni * 16 + ml;
                if (ok) {
                    u16 hb = f2bf(vv[ni]);
                    D[(size_t)row * ldd + col] = hb;
                    if (chk) {
                        float vq = bf2f(hb);
                        float o  = bf2f(copysrc[(size_t)row * 256 + col]);
                        float d = vq - o;
                        d2l += d * d;
                        n2l += o * o;
                    }
                }
            }
        }
        if (chk) {
#pragma unroll
            for (int off = 1; off < 16; off <<= 1) {
                d2l += __shfl_xor(d2l, off);
                n2l += __shfl_xor(n2l, off);
            }
            if (ml == 0) {
                atomicAdd(&rsum[lrow], d2l);
                atomicAdd(&rsum[64 + lrow], n2l);
            }
        }
    }
    if (chk) {
        __syncthreads();
        bool viol = false;
        if (tid < 64) {
            int row = m0 + tid;
            if (row < M) viol = rsum[tid] > THR2 * rsum[64 + tid];
        }
        if (__any(viol) && l == 0) {
            volatile int* f = (volatile int*)chk;
            if (*f == 0) atomicOr(chk, 1);
        }
    }
}

// ---------------- final tiny-N output GEMM: out = (HO @ Wo2 + bo2) * mask ----------
// HO is in pi-layout: stored col cp holds original col
// (cp & ~63) + (cp&3)*16 + ((cp&63)>>2); weight row index uses the original col.

__global__ void k_out(const u16* __restrict__ HO, const float* __restrict__ Wo2,
                      const float* __restrict__ bo2,
                      const int* __restrict__ m1,
                      const int* __restrict__ m2,
                      float* __restrict__ out, int N) {
    __shared__ float w[512 * 7];
    for (int i = threadIdx.x; i < 512 * 7; i += 256) w[i] = Wo2[i];
    __syncthreads();
    int row = blockIdx.x * 4 + (threadIdx.x >> 6);
    if (row >= N) return;
    int l = threadIdx.x & 63;
    uint4 u = *(const uint4*)(HO + (size_t)row * 512 + l * 8);
    float h[8];
    h[0] = lo16(u.x); h[1] = hi16(u.x);
    h[2] = lo16(u.y); h[3] = hi16(u.y);
    h[4] = lo16(u.z); h[5] = hi16(u.z);
    h[6] = lo16(u.w); h[7] = hi16(u.w);
    float a[7] = {0.f, 0.f, 0.f, 0.f, 0.f, 0.f, 0.f};
#pragma unroll
    for (int i = 0; i < 8; ++i) {
        int cp = l * 8 + i;
        int q = cp & 63;
        int orig = (cp & ~63) + ((q & 3) << 4) + (q >> 2);   // pi^-1
        int base = orig * 7;
#pragma unroll
        for (int j = 0; j < 7; ++j) a[j] += h[i] * w[base + j];
    }
    for (int off = 32; off; off >>= 1) {
#pragma unroll
        for (int j = 0; j < 7; ++j) a[j] += __shfl_down(a[j], off);
    }
    if (l == 0) {
        float mm = (m1[row] != 0 && m2[row] != 0) ? 1.f : 0.f;
#pragma unroll
        for (int j = 0; j < 7; ++j) out[(size_t)row * 7 + j] = (a[j] + bo2[j]) * mm;
    }
}

// ---------------- launch ----------------

extern "C" void kernel_launch(void* const* d_in, const int* in_sizes, int n_in,
                              void* d_out, int out_size, void* d_ws, size_t ws_size,
                              hipStream_t stream) {
    const float* nodes   = (const float*)d_in[0];
    const float* arcs    = (const float*)d_in[1];
    const int*   set_mask    = (const int*)d_in[2];
    const int*   output_mask = (const int*)d_in[3];
    const int*   adj_src = (const int*)d_in[4];
    const int*   adj_dst = (const int*)d_in[5];
    const float* adj_vals= (const float*)d_in[6];
    const int*   an_dst  = (const int*)d_in[7];
    const float* an_vals = (const float*)d_in[8];
    const float* state_init = (const float*)d_in[9];
    const float* Ws1 = (const float*)d_in[10];
    const float* bs1 = (const float*)d_in[11];
    const float* Ws2 = (const float*)d_in[12];
    const float* bs2 = (const float*)d_in[13];
    const float* Wo1 = (const float*)d_in[14];
    const float* bo1 = (const float*)d_in[15];
    const float* Wo2 = (const float*)d_in[16];
    const float* bo2 = (const float*)d_in[17];
    float* out = (float*)d_out;

    const int N = in_sizes[2];     // 50000
    const int E = in_sizes[4];     // 640000

    char* ws = (char*)d_ws;
    size_t off = 0;
    auto alloc = [&](size_t bytes) {
        char* p = ws + off;
        off += (bytes + 255) & ~(size_t)255;
        return p;
    };
    u16* SA0 = (u16*)alloc((size_t)N * 256 * 2);
    u16* SA1 = (u16*)alloc((size_t)N * 256 * 2);
    u16* SA2 = (u16*)alloc((size_t)N * 256 * 2);
    u16* CB  = (u16*)alloc((size_t)N * 512 * 2);
    u16* HID = (u16*)alloc((size_t)N * 512 * 2);
    u16* X0  = HID;                 // X0 (N x 320) aliases HID; consumed before HID first write
    u16* FA  = SA0;                 // final [state|nodes] aliases SA0 (free after iter 9)
    u16* W1selT  = (u16*)alloc(512 * 256 * 2);
    u16* W1baseT = (u16*)alloc(512 * 320 * 2);
    u16* W2T     = (u16*)alloc(128 * 512 * 2);
    u16* Wo1T    = (u16*)alloc(512 * 256 * 2);
    int* rpA  = (int*)alloc((size_t)(N + 1) * 4);
    int* curA = (int*)alloc((size_t)N * CPAD * 4);   // padded counters (64B/node)
    int* cntA = (int*)alloc((size_t)N * 4);
    int2* cvA = (int2*)alloc((size_t)E * 8);
    int* rpN  = (int*)alloc((size_t)(N + 1) * 4);
    int* curN = (int*)alloc((size_t)N * CPAD * 4);   // padded counters
    int* cntN = (int*)alloc((size_t)N * 4);
    int2* cvN = (int2*)alloc((size_t)E * 8);
    int* bsA = (int*)alloc(256 * 4);
    int* bsN = (int*)alloc(256 * 4);
    int* flags = (int*)alloc(64 * 4);
    int* anyf = flags;          // [0..10]
    int* cont = flags + 16;     // [0..9]
    (void)ws_size; (void)n_in; (void)out_size;

    const int nb = (N + 255) / 256;
    const int gE = (E + 255) / 256;
    const int gRow = (N + 3) / 4;
    const int gx64 = (N + 63) / 64;

    // init + CSR build
    k_zero2<<<nb, 256, 0, stream>>>(cntA, cntN, N, flags);
    k_hist2<<<gE, 256, 0, stream>>>(adj_dst, an_dst, cntA, cntN, E);
    k_scan_p1<<<nb, 256, 0, stream>>>(cntA, bsA, N);
    k_scan_p2<<<1, 64, 0, stream>>>(bsA, nb, rpA, N);
    k_scan_p3<<<nb, 256, 0, stream>>>(cntA, bsA, rpA, curA, N);
    k_scan_p1<<<nb, 256, 0, stream>>>(cntN, bsN, N);
    k_scan_p2<<<1, 64, 0, stream>>>(bsN, nb, rpN, N);
    k_scan_p3<<<nb, 256, 0, stream>>>(cntN, bsN, rpN, curN, N);
    k_fill2<<<gE, 256, 0, stream>>>(adj_src, adj_dst, adj_vals, curA, cvA,
                                    an_dst, an_vals, curN, cvN, E);
    // merged weight packing (491520 elems)
    k_pack_all<<<1920, 256, 0, stream>>>(Ws1, Ws2, Wo1, W1selT, W1baseT, W2T, Wo1T);
    // merged conversions (3 * N*32 elems)
    k_conv_all<<<(3 * N * 32 + 255) / 256, 256, 0, stream>>>(nodes, state_init,
                                                             X0, SA0, SA2, N);
    // constant aggregations (fused: y=0 nodes, y=1 arcs)
    k_agg_const<<<dim3(gRow, 2), 256, 0, stream>>>(rpA, cvA, nodes,
                                                   rpN, cvN, arcs, X0, N);
    // C_base = X0 @ W1baseT^T + bs1   (no tanh; pi-layout store)
    k_gemm<<<dim3(gx64, 4), 256, 0, stream>>>(X0, 320, W1baseT, 320, bs1,
                                              nullptr, 0, CB, 512, N, 320, 0,
                                              nullptr, 0, nullptr, nullptr,
                                              nullptr, 2);
    // 10 unrolled fixed-point iterations
    u16* SAs[3] = {SA0, SA1, SA2};
    for (int t = 0; t < 10; ++t) {
        u16* curS = SAs[t % 3];
        u16* prvS = SAs[(t + 2) % 3];
        u16* nxtS = SAs[(t + 1) % 3];
        if (t == 0)
            k_check<<<gRow, 256, 0, stream>>>(curS, prvS, N, anyf);
        // (for t>=1, anyf[t] was produced by the previous gemm2's fused check)
        k_spmm_state<<<gRow, 256, 0, stream>>>(rpA, cvA, curS, curS + 128, N,
                                               anyf + t, t ? (cont + t - 1) : nullptr,
                                               cont + t);
        // HID = tanh([state|agg] @ W1selT^T + C_base)   (pi-read CB, pi-store HID)
        k_gemm<<<dim3(gx64, 4), 256, 0, stream>>>(curS, 256, W1selT, 256, nullptr,
                                                  CB, 512, HID, 512, N, 256, 1,
                                                  cont + t, 1, nullptr, nullptr,
                                                  nullptr, 3);
        // next_state = tanh(HID @ W2T'^T + bs2); copy state if converged;
        // fused: anyf[t+1] = any(||next-cur||^2 > THR2*||cur||^2). W2T' has pi on k.
        k_gemm<<<dim3(gx64, 1), 256, 0, stream>>>(HID, 512, W2T, 512, bs2,
                                                  nullptr, 0, nxtS, 256, N, 512, 1,
                                                  cont + t, 2, curS, nxtS,
                                                  anyf + t + 1, 0);
    }
    // final state is in SAs[10 % 3] = SA1
    k_build_fa<<<(N * 64 + 255) / 256, 256, 0, stream>>>(SA1, nodes, FA, N);
    k_gemm<<<dim3(gx64, 4), 256, 0, stream>>>(FA, 256, Wo1T, 256, bo1,
                                              nullptr, 0, HID, 512, N, 256, 1,
                                              nullptr, 0, nullptr, nullptr,
                                              nullptr, 2);
    k_out<<<gRow, 256, 0, stream>>>(HID, Wo2, bo2, set_mask, output_mask, out, N);
}